// Round 5
// baseline (410.408 us; speedup 1.0000x reference)
//
#include <hip/hip_runtime.h>
#include <hip/hip_bf16.h>
#include <cstdint>
#include <math.h>

#define DMODEL 1024
#define SEQ    4096
#define NHEAD  16
#define DK     64
#define KSPLIT 2
#define KVBLK  32
#define KHALF  (SEQ / KSPLIT)

typedef __attribute__((ext_vector_type(8))) short bf16x8;   // 8 bf16 = 4 VGPRs
typedef __attribute__((ext_vector_type(4))) float f32x4;
typedef unsigned short u16;

__device__ __forceinline__ u16 f2bf(float f) {
    union { float f; unsigned int u; } v; v.f = f;
    unsigned int u = v.u;
    u += 0x7FFFu + ((u >> 16) & 1u);   // round-to-nearest-even
    return (u16)(u >> 16);
}
__device__ __forceinline__ float bf2f(u16 h) {
    union { unsigned int u; float f; } v; v.u = ((unsigned int)h) << 16;
    return v.f;
}
__device__ __forceinline__ unsigned int pk_bf16(float a, float b) {
    union { __hip_bfloat162 h; unsigned int u; } v;
    v.h = __float22bfloat162_rn(make_float2(a, b));
    return v.u;
}
// raw v_exp_f32 = 2^x (Q is pre-scaled by 1/8 * log2(e) so this computes e^s)
__device__ __forceinline__ float fast_exp2(float x) {
    float r; asm("v_exp_f32 %0, %1" : "=v"(r) : "v"(x)); return r;
}

// Fallback marker if ws_size too small (diagnostic).
__global__ __launch_bounds__(256) void fallback_marker(float* __restrict__ out, int n) {
    int i = blockIdx.x * 256 + threadIdx.x;
    if (i < n) out[i] = (i == 0) ? 12345.0f : 0.0f;
}

// ---------------------------------------------------------------------------
// fp32 -> (hi, lo) bf16 split, elementwise (float4 granularity).
// ---------------------------------------------------------------------------
__device__ __forceinline__ void split4_store(const float* __restrict__ in,
                                             u16* __restrict__ hi,
                                             u16* __restrict__ lo, int i) {
    float4 v = ((const float4*)in)[i];
    u16 h0 = f2bf(v.x), h1 = f2bf(v.y), h2 = f2bf(v.z), h3 = f2bf(v.w);
    ushort4 hv; hv.x = h0; hv.y = h1; hv.z = h2; hv.w = h3;
    ushort4 lv;
    lv.x = f2bf(v.x - bf2f(h0)); lv.y = f2bf(v.y - bf2f(h1));
    lv.z = f2bf(v.z - bf2f(h2)); lv.w = f2bf(v.w - bf2f(h3));
    ((ushort4*)hi)[i] = hv;
    ((ushort4*)lo)[i] = lv;
}

__global__ __launch_bounds__(256) void split_kernel(const float* __restrict__ in,
                                                    u16* __restrict__ hi,
                                                    u16* __restrict__ lo, int n4) {
    int i = blockIdx.x * 256 + threadIdx.x;
    if (i < n4) split4_store(in, hi, lo, i);
}

// Activation (y=0) + weight (y=1) split fused into one launch.
__global__ __launch_bounds__(256) void split_pair(const float* __restrict__ a_in,
                                                  u16* __restrict__ a_hi,
                                                  u16* __restrict__ a_lo, int a_n4,
                                                  const float* __restrict__ w_in,
                                                  u16* __restrict__ w_hi,
                                                  u16* __restrict__ w_lo, int w_n4) {
    int i = blockIdx.x * 256 + threadIdx.x;
    if (blockIdx.y == 0) {
        if (i < a_n4) split4_store(a_in, a_hi, a_lo, i);
    } else {
        if (i < w_n4) split4_store(w_in, w_hi, w_lo, i);
    }
}

// ---------------------------------------------------------------------------
// hi/lo-split MFMA GEMM core v2 (round-0/2 PROVEN, 256 threads): 128x64
// tile, wave owns 32 rows (2 m-frags) x 64 cols. Per-output accumulation
// order fixed. (512-thread v4 measured SLOWER in r4: LDS read traffic x2.)
// ---------------------------------------------------------------------------
__device__ __forceinline__ void gemm_core_hl2(const u16* __restrict__ aHi,
                                              const u16* __restrict__ aLo,
                                              const u16* __restrict__ bHi,
                                              const u16* __restrict__ bLo,
                                              int bm, int bn,
                                              f32x4 (&acc)[2][4]) {
    __shared__ u16 sAh[128 * 72], sAl[128 * 72];   // 18 KB each
    __shared__ u16 sBh[64 * 72],  sBl[64 * 72];    // 9 KB each  (54 KB total)

    const int tid  = threadIdx.x;
    const int wave = tid >> 6;
    const int lane = tid & 63;
    const int quad = lane >> 4;
    const int l15  = lane & 15;
    const int srow = tid >> 2;          // 0..63
    const int scol = (tid & 3) * 16;    // 0,16,32,48

    const u16* pAh0 = aHi + (size_t)(bm + srow) * DMODEL + scol;
    const u16* pAh1 = aHi + (size_t)(bm + 64 + srow) * DMODEL + scol;
    const u16* pAl0 = aLo + (size_t)(bm + srow) * DMODEL + scol;
    const u16* pAl1 = aLo + (size_t)(bm + 64 + srow) * DMODEL + scol;
    const u16* pBh  = bHi + (size_t)(bn + srow) * DMODEL + scol;
    const u16* pBl  = bLo + (size_t)(bn + srow) * DMODEL + scol;

    for (int k0 = 0; k0 < DMODEL; k0 += 64) {
        uint4 ah00 = *(const uint4*)(pAh0 + k0);
        uint4 ah01 = *(const uint4*)(pAh0 + k0 + 8);
        uint4 ah10 = *(const uint4*)(pAh1 + k0);
        uint4 ah11 = *(const uint4*)(pAh1 + k0 + 8);
        uint4 al00 = *(const uint4*)(pAl0 + k0);
        uint4 al01 = *(const uint4*)(pAl0 + k0 + 8);
        uint4 al10 = *(const uint4*)(pAl1 + k0);
        uint4 al11 = *(const uint4*)(pAl1 + k0 + 8);
        uint4 bh0  = *(const uint4*)(pBh + k0);
        uint4 bh1  = *(const uint4*)(pBh + k0 + 8);
        uint4 bl0  = *(const uint4*)(pBl + k0);
        uint4 bl1  = *(const uint4*)(pBl + k0 + 8);

        __syncthreads();
        *(uint4*)&sAh[srow * 72 + scol]            = ah00;
        *(uint4*)&sAh[srow * 72 + scol + 8]        = ah01;
        *(uint4*)&sAh[(64 + srow) * 72 + scol]     = ah10;
        *(uint4*)&sAh[(64 + srow) * 72 + scol + 8] = ah11;
        *(uint4*)&sAl[srow * 72 + scol]            = al00;
        *(uint4*)&sAl[srow * 72 + scol + 8]        = al01;
        *(uint4*)&sAl[(64 + srow) * 72 + scol]     = al10;
        *(uint4*)&sAl[(64 + srow) * 72 + scol + 8] = al11;
        *(uint4*)&sBh[srow * 72 + scol]            = bh0;
        *(uint4*)&sBh[srow * 72 + scol + 8]        = bh1;
        *(uint4*)&sBl[srow * 72 + scol]            = bl0;
        *(uint4*)&sBl[srow * 72 + scol + 8]        = bl1;
        __syncthreads();

#pragma unroll
        for (int c = 0; c < 2; c++) {
            bf16x8 ah[2], al[2];
#pragma unroll
            for (int m = 0; m < 2; m++) {
                const int aoff = (wave * 32 + m * 16 + l15) * 72 + c * 32 + quad * 8;
                ah[m] = *(const bf16x8*)&sAh[aoff];
                al[m] = *(const bf16x8*)&sAl[aoff];
            }
#pragma unroll
            for (int nt = 0; nt < 4; nt++) {
                const int boff = (nt * 16 + l15) * 72 + c * 32 + quad * 8;
                bf16x8 bhf = *(const bf16x8*)&sBh[boff];
                bf16x8 blf = *(const bf16x8*)&sBl[boff];
#pragma unroll
                for (int m = 0; m < 2; m++) {
                    acc[m][nt] = __builtin_amdgcn_mfma_f32_16x16x32_bf16(ah[m], bhf, acc[m][nt], 0, 0, 0);
                    acc[m][nt] = __builtin_amdgcn_mfma_f32_16x16x32_bf16(ah[m], blf, acc[m][nt], 0, 0, 0);
                    acc[m][nt] = __builtin_amdgcn_mfma_f32_16x16x32_bf16(al[m], bhf, acc[m][nt], 0, 0, 0);
                }
            }
        }
    }
}

__global__ __launch_bounds__(256) void proj_hl_bf(const u16* __restrict__ aHi,
                                                  const u16* __restrict__ aLo,
                                                  const u16* __restrict__ bHi,
                                                  const u16* __restrict__ bLo,
                                                  u16* __restrict__ C,
                                                  int ldc, float scale) {
    const int bm = blockIdx.x * 128;
    const int bn = blockIdx.y * 64;
    f32x4 acc[2][4] = {};
    gemm_core_hl2(aHi, aLo, bHi, bLo, bm, bn, acc);
    const int lane = threadIdx.x & 63;
    const int wave = threadIdx.x >> 6;
    const int quad = lane >> 4;
    const int l15  = lane & 15;
#pragma unroll
    for (int m = 0; m < 2; m++)
#pragma unroll
        for (int nt = 0; nt < 4; nt++) {
            int col = bn + nt * 16 + l15;
#pragma unroll
            for (int r = 0; r < 4; r++) {
                int row = bm + wave * 32 + m * 16 + quad * 4 + r;
                C[(size_t)row * ldc + col] = f2bf(acc[m][nt][r] * scale);
            }
        }
}

__global__ __launch_bounds__(256) void proj_hl_f32(const u16* __restrict__ aHi,
                                                   const u16* __restrict__ aLo,
                                                   const u16* __restrict__ bHi,
                                                   const u16* __restrict__ bLo,
                                                   float* __restrict__ C) {
    const int bm = blockIdx.x * 128;
    const int bn = blockIdx.y * 64;
    f32x4 acc[2][4] = {};
    gemm_core_hl2(aHi, aLo, bHi, bLo, bm, bn, acc);
    const int lane = threadIdx.x & 63;
    const int wave = threadIdx.x >> 6;
    const int quad = lane >> 4;
    const int l15  = lane & 15;
#pragma unroll
    for (int m = 0; m < 2; m++)
#pragma unroll
        for (int nt = 0; nt < 4; nt++) {
            int col = bn + nt * 16 + l15;
#pragma unroll
            for (int r = 0; r < 4; r++) {
                int row = bm + wave * 32 + m * 16 + quad * 4 + r;
                C[(size_t)row * DMODEL + col] = acc[m][nt][r];
            }
        }
}

// ---------------------------------------------------------------------------
// MFMA flash attention v6 (KEY-SPLIT): grid (32, NHEAD*KSPLIT) = 1024 blocks,
// 256 threads. Each block: 128 q-rows x one head x one KEY HALF (2048 keys).
// Staging volume unchanged vs r2 (disjoint key ranges) but 4 blocks/CU.
// KVBLK=32 -> LDS 28.7 KB (K dbuf 9.2 + V dbuf 10.2 + P 9.2) so LDS allows 5.
// Writes UNNORMALIZED O_num (bf16 hi/lo) + l partials; merge normalizes.
// Q pre-scaled by (1/8)*log2(e); v_exp_f32(s) = e^{s_orig}.
// ---------------------------------------------------------------------------
#define PSTs 36   // sP row stride (u16)
#define VST  40   // sV row stride (u16)
#define KST  72   // sK row stride (u16)

__global__ __launch_bounds__(256) void attn_part(const u16* __restrict__ Q,
                                                 const u16* __restrict__ K,
                                                 const u16* __restrict__ Vt,
                                                 u16* __restrict__ N0h,
                                                 u16* __restrict__ N0l,
                                                 u16* __restrict__ N1h,
                                                 u16* __restrict__ N1l,
                                                 float* __restrict__ Lbuf) {
    __shared__ u16 sK[2][KVBLK * KST];   // 9216 B
    __shared__ u16 sV[2][64 * VST];      // 10240 B
    __shared__ u16 sP[4 * 32 * PSTs];    // 9216 B   (28672 B total)

    // XCD-aware bijective swizzle: 1024 blocks, chunk 128 per XCD
    // (= one key-half of 4 whole heads: K+V working set 2 MB < 4 MB L2).
    const int lin   = blockIdx.y * gridDim.x + blockIdx.x;  // grid (32, 32)
    const int swz   = (lin & 7) * 128 + (lin >> 3);
    const int ks    = swz >> 9;            // 0..1  key-half
    const int head  = (swz >> 5) & 15;     // 0..15
    const int q0    = (swz & 31) * 128;
    const int kbase = ks * KHALF;

    const int tid  = threadIdx.x;
    const int wave = tid >> 6;
    const int lane = tid & 63;
    const int quad = lane >> 4;
    const int l15  = lane & 15;
    const int srK  = tid >> 3;           // 0..31  (K tile row = key)
    const int scK  = (tid & 7) * 8;      // 0..56  (K tile col = d)
    const int srV  = tid >> 2;           // 0..63  (V tile row = d)
    const int scV  = (tid & 3) * 8;      // 0..24  (V tile col = key)

    bf16x8 qf[2][2];
#pragma unroll
    for (int m = 0; m < 2; m++) {
        const u16* qb = Q + (size_t)(q0 + wave * 32 + m * 16 + l15) * DMODEL + head * DK;
        qf[m][0] = *(const bf16x8*)(qb + quad * 8);
        qf[m][1] = *(const bf16x8*)(qb + 32 + quad * 8);
    }

    f32x4 oacc[2][4] = {};
    float l_part[2][4] = {};

    const u16* Kst = K  + (size_t)(kbase + srK) * DMODEL + head * DK + scK;
    const u16* Vst = Vt + (size_t)(head * DK + srV) * SEQ + kbase + scV;
    u16* sPw = sP + wave * 32 * PSTs;

    // Prologue: stage tile 0 into buffer 0 (one uint4 each).
    {
        uint4 kv = *(const uint4*)Kst;
        uint4 vv = *(const uint4*)Vst;
        *(uint4*)&sK[0][srK * KST + scK] = kv;
        *(uint4*)&sV[0][srV * VST + scV] = vv;
    }
    __syncthreads();

    int cur = 0;
    for (int k0 = 0; k0 < KHALF; k0 += KVBLK) {
        uint4 nkv, nvv;
        const bool has_next = (k0 + KVBLK < KHALF);
        if (has_next) {
            nkv = *(const uint4*)(Kst + (size_t)(k0 + KVBLK) * DMODEL);
            nvv = *(const uint4*)(Vst + k0 + KVBLK);
        }

        // --- QK^T from sK[cur] (32 keys = 2 nt tiles) ---
        f32x4 s[2][2] = {};
#pragma unroll
        for (int nt = 0; nt < 2; nt++) {
            bf16x8 b0 = *(const bf16x8*)&sK[cur][(nt * 16 + l15) * KST + quad * 8];
            bf16x8 b1 = *(const bf16x8*)&sK[cur][(nt * 16 + l15) * KST + 32 + quad * 8];
#pragma unroll
            for (int m = 0; m < 2; m++) {
                s[m][nt] = __builtin_amdgcn_mfma_f32_16x16x32_bf16(qf[m][0], b0, s[m][nt], 0, 0, 0);
                s[m][nt] = __builtin_amdgcn_mfma_f32_16x16x32_bf16(qf[m][1], b1, s[m][nt], 0, 0, 0);
            }
        }

        // --- softmax numerator -> per-wave P tile [32 q][32 key] ---
#pragma unroll
        for (int m = 0; m < 2; m++)
#pragma unroll
            for (int nt = 0; nt < 2; nt++) {
                float p0 = fast_exp2(s[m][nt][0]);
                float p1 = fast_exp2(s[m][nt][1]);
                float p2 = fast_exp2(s[m][nt][2]);
                float p3 = fast_exp2(s[m][nt][3]);
                l_part[m][0] += p0; l_part[m][1] += p1;
                l_part[m][2] += p2; l_part[m][3] += p3;
                unsigned int u01 = pk_bf16(p0, p1);
                unsigned int u23 = pk_bf16(p2, p3);
                const int rb   = m * 16 + quad * 4;
                const int colo = nt * 16 + l15;
                sPw[(rb + 0) * PSTs + colo] = (u16)(u01 & 0xFFFFu);
                sPw[(rb + 1) * PSTs + colo] = (u16)(u01 >> 16);
                sPw[(rb + 2) * PSTs + colo] = (u16)(u23 & 0xFFFFu);
                sPw[(rb + 3) * PSTs + colo] = (u16)(u23 >> 16);
            }

        // --- PV from sV[cur] (k = 32 keys, single pass) ---
        {
            bf16x8 pf0 = *(const bf16x8*)&sPw[(0 * 16 + l15) * PSTs + quad * 8];
            bf16x8 pf1 = *(const bf16x8*)&sPw[(1 * 16 + l15) * PSTs + quad * 8];
#pragma unroll
            for (int nt = 0; nt < 4; nt++) {
                bf16x8 vf = *(const bf16x8*)&sV[cur][(nt * 16 + l15) * VST + quad * 8];
                oacc[0][nt] = __builtin_amdgcn_mfma_f32_16x16x32_bf16(pf0, vf, oacc[0][nt], 0, 0, 0);
                oacc[1][nt] = __builtin_amdgcn_mfma_f32_16x16x32_bf16(pf1, vf, oacc[1][nt], 0, 0, 0);
            }
        }

        // --- stage next tile into the other buffer; single barrier ---
        if (has_next) {
            const int nxt = cur ^ 1;
            *(uint4*)&sK[nxt][srK * KST + scK] = nkv;
            *(uint4*)&sV[nxt][srV * VST + scV] = nvv;
        }
        __syncthreads();
        cur ^= 1;
    }

    u16* __restrict__ Nh = ks ? N1h : N0h;
    u16* __restrict__ Nl = ks ? N1l : N0l;

#pragma unroll
    for (int m = 0; m < 2; m++) {
        float l_i[4];
#pragma unroll
        for (int r = 0; r < 4; r++) {
            float l = l_part[m][r];
            l += __shfl_xor(l, 1);
            l += __shfl_xor(l, 2);
            l += __shfl_xor(l, 4);
            l += __shfl_xor(l, 8);
            l_i[r] = l;
        }
        if (l15 == 0) {
#pragma unroll
            for (int r = 0; r < 4; r++) {
                int row = q0 + wave * 32 + m * 16 + quad * 4 + r;
                Lbuf[((size_t)ks * SEQ + row) * NHEAD + head] = l_i[r];
            }
        }
#pragma unroll
        for (int nt = 0; nt < 4; nt++) {
            int col = head * DK + nt * 16 + l15;
#pragma unroll
            for (int r = 0; r < 4; r++) {
                int row = q0 + wave * 32 + m * 16 + quad * 4 + r;
                float on = oacc[m][nt][r];       // unnormalized numerator
                u16 h = f2bf(on);
                Nh[(size_t)row * DMODEL + col] = h;
                Nl[(size_t)row * DMODEL + col] = f2bf(on - bf2f(h));
            }
        }
    }
}

// ---------------------------------------------------------------------------
// Merge: AO = (O_num0 + O_num1) / (l0 + l1), element-wise, IN PLACE into the
// split-1 buffers (each location read+written only by its own thread).
// ---------------------------------------------------------------------------
__global__ __launch_bounds__(256) void attn_merge(const u16* __restrict__ n0h,
                                                  const u16* __restrict__ n0l,
                                                  u16* __restrict__ n1h,   // = AOh out
                                                  u16* __restrict__ n1l,   // = AOl out
                                                  const float* __restrict__ Lbuf) {
    const int i8   = blockIdx.x * 256 + threadIdx.x;   // 0 .. SEQ*DMODEL/8-1
    const int base = i8 * 8;
    const int row  = base >> 10;            // / DMODEL
    const int head = (base & 1023) >> 6;    // col / DK (8-chunk stays in one head)
    const float l0 = Lbuf[(size_t)row * NHEAD + head];
    const float l1 = Lbuf[((size_t)SEQ + row) * NHEAD + head];
    const float inv = 1.0f / (l0 + l1);

    union U8 { uint4 v; u16 s[8]; };
    U8 ah, al, bh, bl, oh, ol;
    ah.v = *(const uint4*)(n0h + base);
    al.v = *(const uint4*)(n0l + base);
    bh.v = *(const uint4*)(n1h + base);
    bl.v = *(const uint4*)(n1l + base);
#pragma unroll
    for (int j = 0; j < 8; j++) {
        float o = ((bf2f(ah.s[j]) + bf2f(al.s[j])) + (bf2f(bh.s[j]) + bf2f(bl.s[j]))) * inv;
        u16 h = f2bf(o);
        oh.s[j] = h;
        ol.s[j] = f2bf(o - bf2f(h));
    }
    *(uint4*)(n1h + base) = oh.v;
    *(uint4*)(n1l + base) = ol.v;
}

// ---------------------------------------------------------------------------
extern "C" void kernel_launch(void* const* d_in, const int* in_sizes, int n_in,
                              void* d_out, int out_size, void* d_ws, size_t ws_size,
                              hipStream_t stream) {
    const float* query = (const float*)d_in[0];
    const float* key_t = (const float*)d_in[1];
    const float* value = (const float*)d_in[2];
    const float* wq    = (const float*)d_in[3];
    const float* wk    = (const float*)d_in[4];
    const float* wv    = (const float*)d_in[5];
    const float* wo    = (const float*)d_in[6];
    float* out = (float*)d_out;

    const size_t ACT_N = (size_t)SEQ * DMODEL;
    const size_t W_N   = (size_t)DMODEL * DMODEL;
    const size_t NEED  = 4 * ACT_N * sizeof(float);   // 64 MB (verified available)

    if (d_ws == nullptr || ws_size < NEED) {
        fallback_marker<<<dim3((out_size + 255) / 256), dim3(256), 0, stream>>>(out, out_size);
        return;
    }

    u16* ACT_HI = (u16*)d_ws;          // 0-8 MB   (phased; O_num0 hi at attn time)
    u16* ACT_LO = ACT_HI + ACT_N;      // 8-16 MB  (O_num0 lo)
    u16* W_HI   = ACT_LO + ACT_N;      // 16-18 MB (phased)
    u16* W_LO   = W_HI + W_N;          // 18-20 MB
    u16* Qb     = W_LO + W_N;          // 20-28 MB bf16 Q (pre-scaled 1/8*log2e)
    u16* Kb     = Qb + ACT_N;          // 28-36 MB bf16 K
    u16* Vt     = Kb + ACT_N;          // 36-44 MB bf16 V^T [DMODEL][SEQ]
    u16* AO_HI  = Vt + ACT_N;          // 44-52 MB (O_num1 hi -> merged AO hi)
    u16* AO_LO  = AO_HI + ACT_N;       // 52-60 MB (O_num1 lo -> merged AO lo)
    float* Lbuf = (float*)((char*)d_ws + 60u * 1024u * 1024u);  // 60-60.5 MB (l partials)

    const int ACT4 = (int)(ACT_N / 4);
    const int W4   = (int)(W_N / 4);
    dim3 blk(256);
    dim3 pairg((ACT4 + 255) / 256, 2);
    dim3 wg((W4 + 255) / 256);

    const float QSCALE = 0.125f * 1.44269504f;   // 1/sqrt(dk) * log2(e)

    split_pair<<<pairg, blk, 0, stream>>>(query, ACT_HI, ACT_LO, ACT4, wq, W_HI, W_LO, W4);
    proj_hl_bf<<<dim3(SEQ / 128, DMODEL / 64), blk, 0, stream>>>(
        ACT_HI, ACT_LO, W_HI, W_LO, Qb, DMODEL, QSCALE);

    split_pair<<<pairg, blk, 0, stream>>>(key_t, ACT_HI, ACT_LO, ACT4, wk, W_HI, W_LO, W4);
    proj_hl_bf<<<dim3(SEQ / 128, DMODEL / 64), blk, 0, stream>>>(
        ACT_HI, ACT_LO, W_HI, W_LO, Kb, DMODEL, 1.0f);

    split_pair<<<pairg, blk, 0, stream>>>(value, ACT_HI, ACT_LO, ACT4, wv, W_HI, W_LO, W4);
    proj_hl_bf<<<dim3(DMODEL / 128, SEQ / 64), blk, 0, stream>>>(
        W_HI, W_LO, ACT_HI, ACT_LO, Vt, SEQ, 1.0f);

    // Key-split attention: ACT/W regions are dead here; partials overwrite them.
    attn_part<<<dim3(SEQ / 128, NHEAD * KSPLIT), blk, 0, stream>>>(
        Qb, Kb, Vt, ACT_HI, ACT_LO, AO_HI, AO_LO, Lbuf);
    attn_merge<<<dim3((int)(ACT_N / 8 / 256)), blk, 0, stream>>>(
        ACT_HI, ACT_LO, AO_HI, AO_LO, Lbuf);

    split_kernel<<<wg, blk, 0, stream>>>(wo, W_HI, W_LO, W4);
    proj_hl_f32<<<dim3(SEQ / 128, DMODEL / 64), blk, 0, stream>>>(
        AO_HI, AO_LO, W_HI, W_LO, out);
}

// Round 6
// 409.495 us; speedup vs baseline: 1.0022x; 1.0022x over previous
//
#include <hip/hip_runtime.h>
#include <hip/hip_bf16.h>
#include <cstdint>
#include <math.h>

#define DMODEL 1024
#define SEQ    4096
#define NHEAD  16
#define DK     64

typedef __attribute__((ext_vector_type(8))) short bf16x8;   // 8 bf16 = 4 VGPRs
typedef __attribute__((ext_vector_type(4))) float f32x4;
typedef unsigned short u16;

__device__ __forceinline__ u16 f2bf(float f) {
    union { float f; unsigned int u; } v; v.f = f;
    unsigned int u = v.u;
    u += 0x7FFFu + ((u >> 16) & 1u);   // round-to-nearest-even
    return (u16)(u >> 16);
}
__device__ __forceinline__ float bf2f(u16 h) {
    union { unsigned int u; float f; } v; v.u = ((unsigned int)h) << 16;
    return v.f;
}
__device__ __forceinline__ unsigned int pk_bf16(float a, float b) {
    union { __hip_bfloat162 h; unsigned int u; } v;
    v.h = __float22bfloat162_rn(make_float2(a, b));
    return v.u;
}
// raw v_exp_f32 = 2^x (Q is pre-scaled by 1/8 * log2(e) so this computes e^s)
__device__ __forceinline__ float fast_exp2(float x) {
    float r; asm("v_exp_f32 %0, %1" : "=v"(r) : "v"(x)); return r;
}

// Async global->LDS DMA, 16B per lane. LDS dest is wave-uniform base +
// lane*16 (m104); per-lane GLOBAL source chosen to match linear layout.
__device__ __forceinline__ void gload16(const u16* g, u16* l) {
    __builtin_amdgcn_global_load_lds(
        (const __attribute__((address_space(1))) void*)g,
        (__attribute__((address_space(3))) void*)l, 16, 0, 0);
}

// Fallback marker if ws_size too small (diagnostic).
__global__ __launch_bounds__(256) void fallback_marker(float* __restrict__ out, int n) {
    int i = blockIdx.x * 256 + threadIdx.x;
    if (i < n) out[i] = (i == 0) ? 12345.0f : 0.0f;
}

// ---------------------------------------------------------------------------
// fp32 -> (hi, lo) bf16 split, elementwise (float4 granularity).
// ---------------------------------------------------------------------------
__device__ __forceinline__ void split4_store(const float* __restrict__ in,
                                             u16* __restrict__ hi,
                                             u16* __restrict__ lo, int i) {
    float4 v = ((const float4*)in)[i];
    u16 h0 = f2bf(v.x), h1 = f2bf(v.y), h2 = f2bf(v.z), h3 = f2bf(v.w);
    ushort4 hv; hv.x = h0; hv.y = h1; hv.z = h2; hv.w = h3;
    ushort4 lv;
    lv.x = f2bf(v.x - bf2f(h0)); lv.y = f2bf(v.y - bf2f(h1));
    lv.z = f2bf(v.z - bf2f(h2)); lv.w = f2bf(v.w - bf2f(h3));
    ((ushort4*)hi)[i] = hv;
    ((ushort4*)lo)[i] = lv;
}

__global__ __launch_bounds__(256) void split_kernel(const float* __restrict__ in,
                                                    u16* __restrict__ hi,
                                                    u16* __restrict__ lo, int n4) {
    int i = blockIdx.x * 256 + threadIdx.x;
    if (i < n4) split4_store(in, hi, lo, i);
}

// Activation (y=0) + weight (y=1) split fused into one launch.
__global__ __launch_bounds__(256) void split_pair(const float* __restrict__ a_in,
                                                  u16* __restrict__ a_hi,
                                                  u16* __restrict__ a_lo, int a_n4,
                                                  const float* __restrict__ w_in,
                                                  u16* __restrict__ w_hi,
                                                  u16* __restrict__ w_lo, int w_n4) {
    int i = blockIdx.x * 256 + threadIdx.x;
    if (blockIdx.y == 0) {
        if (i < a_n4) split4_store(a_in, a_hi, a_lo, i);
    } else {
        if (i < w_n4) split4_store(w_in, w_hi, w_lo, i);
    }
}

// ---------------------------------------------------------------------------
// hi/lo-split MFMA GEMM core v5: m97 recipe. Same 128x64 tile, 256 threads,
// same per-output MFMA order as proven v2 (bit-identical results), but
// staging via global_load_lds width=16 (12 DMA issues/k-step) into LINEAR
// [rows][64] LDS (48 KB). Removes 12 b128 ds_writes + 48 staging VGPRs per
// k-step from the DS/VALU pipes (m97: 517->874 TF on this structure).
// Read conflicts from the linear stride are the m97-accepted trade.
// ---------------------------------------------------------------------------
__device__ __forceinline__ void gemm_core_hl5(const u16* __restrict__ aHi,
                                              const u16* __restrict__ aLo,
                                              const u16* __restrict__ bHi,
                                              const u16* __restrict__ bLo,
                                              int bm, int bn,
                                              f32x4 (&acc)[2][4]) {
    __shared__ u16 sAh[128 * 64], sAl[128 * 64];   // 16 KB each
    __shared__ u16 sBh[64 * 64],  sBl[64 * 64];    // 8 KB each  (48 KB total)

    const int tid  = threadIdx.x;
    const int wave = tid >> 6;
    const int lane = tid & 63;
    const int quad = lane >> 4;
    const int l15  = lane & 15;
    const int rsub = lane >> 3;          // 0..7   (row within 8-row wave chunk)
    const int csub = (lane & 7) * 8;     // 0..56  (u16 col, 16B granule)

    // Per-lane global sources; LDS bases are wave-uniform.
    const u16* gAh = aHi + (size_t)(bm + wave * 8 + rsub) * DMODEL + csub;
    const u16* gAl = aLo + (size_t)(bm + wave * 8 + rsub) * DMODEL + csub;
    const u16* gBh = bHi + (size_t)(bn + wave * 8 + rsub) * DMODEL + csub;
    const u16* gBl = bLo + (size_t)(bn + wave * 8 + rsub) * DMODEL + csub;
    u16* lAh = &sAh[(wave * 8) * 64];
    u16* lAl = &sAl[(wave * 8) * 64];
    u16* lBh = &sBh[(wave * 8) * 64];
    u16* lBl = &sBl[(wave * 8) * 64];

    for (int k0 = 0; k0 < DMODEL; k0 += 64) {
        __syncthreads();   // all reads of previous tile done before overwrite
#pragma unroll
        for (int j = 0; j < 4; j++) {
            gload16(gAh + (size_t)(j * 32) * DMODEL + k0, lAh + j * 32 * 64);
            gload16(gAl + (size_t)(j * 32) * DMODEL + k0, lAl + j * 32 * 64);
        }
#pragma unroll
        for (int j = 0; j < 2; j++) {
            gload16(gBh + (size_t)(j * 32) * DMODEL + k0, lBh + j * 32 * 64);
            gload16(gBl + (size_t)(j * 32) * DMODEL + k0, lBl + j * 32 * 64);
        }
        __syncthreads();   // drains vmcnt: tile staged

#pragma unroll
        for (int c = 0; c < 2; c++) {
            bf16x8 ah[2], al[2];
#pragma unroll
            for (int m = 0; m < 2; m++) {
                const int aoff = (wave * 32 + m * 16 + l15) * 64 + c * 32 + quad * 8;
                ah[m] = *(const bf16x8*)&sAh[aoff];
                al[m] = *(const bf16x8*)&sAl[aoff];
            }
#pragma unroll
            for (int nt = 0; nt < 4; nt++) {
                const int boff = (nt * 16 + l15) * 64 + c * 32 + quad * 8;
                bf16x8 bhf = *(const bf16x8*)&sBh[boff];
                bf16x8 blf = *(const bf16x8*)&sBl[boff];
#pragma unroll
                for (int m = 0; m < 2; m++) {
                    acc[m][nt] = __builtin_amdgcn_mfma_f32_16x16x32_bf16(ah[m], bhf, acc[m][nt], 0, 0, 0);
                    acc[m][nt] = __builtin_amdgcn_mfma_f32_16x16x32_bf16(ah[m], blf, acc[m][nt], 0, 0, 0);
                    acc[m][nt] = __builtin_amdgcn_mfma_f32_16x16x32_bf16(al[m], bhf, acc[m][nt], 0, 0, 0);
                }
            }
        }
    }
}

__global__ __launch_bounds__(256) void proj_hl_bf(const u16* __restrict__ aHi,
                                                  const u16* __restrict__ aLo,
                                                  const u16* __restrict__ bHi,
                                                  const u16* __restrict__ bLo,
                                                  u16* __restrict__ C,
                                                  int ldc, float scale) {
    const int bm = blockIdx.x * 128;
    const int bn = blockIdx.y * 64;
    f32x4 acc[2][4] = {};
    gemm_core_hl5(aHi, aLo, bHi, bLo, bm, bn, acc);
    const int lane = threadIdx.x & 63;
    const int wave = threadIdx.x >> 6;
    const int quad = lane >> 4;
    const int l15  = lane & 15;
#pragma unroll
    for (int m = 0; m < 2; m++)
#pragma unroll
        for (int nt = 0; nt < 4; nt++) {
            int col = bn + nt * 16 + l15;
#pragma unroll
            for (int r = 0; r < 4; r++) {
                int row = bm + wave * 32 + m * 16 + quad * 4 + r;
                C[(size_t)row * ldc + col] = f2bf(acc[m][nt][r] * scale);
            }
        }
}

__global__ __launch_bounds__(256) void proj_hl_f32(const u16* __restrict__ aHi,
                                                   const u16* __restrict__ aLo,
                                                   const u16* __restrict__ bHi,
                                                   const u16* __restrict__ bLo,
                                                   float* __restrict__ C) {
    const int bm = blockIdx.x * 128;
    const int bn = blockIdx.y * 64;
    f32x4 acc[2][4] = {};
    gemm_core_hl5(aHi, aLo, bHi, bLo, bm, bn, acc);
    const int lane = threadIdx.x & 63;
    const int wave = threadIdx.x >> 6;
    const int quad = lane >> 4;
    const int l15  = lane & 15;
#pragma unroll
    for (int m = 0; m < 2; m++)
#pragma unroll
        for (int nt = 0; nt < 4; nt++) {
            int col = bn + nt * 16 + l15;
#pragma unroll
            for (int r = 0; r < 4; r++) {
                int row = bm + wave * 32 + m * 16 + quad * 4 + r;
                C[(size_t)row * DMODEL + col] = acc[m][nt][r];
            }
        }
}

// ---------------------------------------------------------------------------
// MFMA flash attention v4 (round-2 PROVEN, byte-identical): 256 threads,
// wave owns 32 q-rows, dbuf K/V, single barrier per k-step, XCD swizzle.
// ---------------------------------------------------------------------------
#define PST 68   // sP row stride (u16)

__global__ __launch_bounds__(256) void attn_mfma(const u16* __restrict__ Q,
                                                 const u16* __restrict__ K,
                                                 const u16* __restrict__ Vt,
                                                 u16* __restrict__ AOh,
                                                 u16* __restrict__ AOl) {
    __shared__ u16 sK[2][64 * 72];       // K tile [key][d]   9 KB x2
    __shared__ u16 sV[2][64 * 72];       // V tile [d][key]   9 KB x2
    __shared__ u16 sP[4 * 32 * PST];     // per-wave P [32][key] 17 KB

    // XCD-aware bijective swizzle: grid (32,16) = 512 blocks, chunk = 64.
    const int lin  = blockIdx.y * gridDim.x + blockIdx.x;
    const int swz  = (lin & 7) * 64 + (lin >> 3);
    const int head = swz >> 5;           // 0..15; 2 whole heads per XCD
    const int q0   = (swz & 31) * 128;

    const int tid  = threadIdx.x;
    const int wave = tid >> 6;
    const int lane = tid & 63;
    const int quad = lane >> 4;
    const int l15  = lane & 15;
    const int srow = tid >> 2;           // 0..63
    const int scol = (tid & 3) * 16;     // 0,16,32,48

    bf16x8 qf[2][2];
#pragma unroll
    for (int m = 0; m < 2; m++) {
        const u16* qb = Q + (size_t)(q0 + wave * 32 + m * 16 + l15) * DMODEL + head * DK;
        qf[m][0] = *(const bf16x8*)(qb + quad * 8);
        qf[m][1] = *(const bf16x8*)(qb + 32 + quad * 8);
    }

    f32x4 oacc[2][4] = {};
    float l_part[2][4] = {};

    const u16* Kst = K  + (size_t)srow * DMODEL + head * DK + scol;
    const u16* Vst = Vt + (size_t)(head * DK + srow) * SEQ + scol;
    u16* sPw = sP + wave * 32 * PST;

    // Prologue: stage tile 0 into buffer 0.
    {
        uint4 kv0 = *(const uint4*)(Kst);
        uint4 kv1 = *(const uint4*)(Kst + 8);
        uint4 vv0 = *(const uint4*)(Vst);
        uint4 vv1 = *(const uint4*)(Vst + 8);
        *(uint4*)&sK[0][srow * 72 + scol]     = kv0;
        *(uint4*)&sK[0][srow * 72 + scol + 8] = kv1;
        *(uint4*)&sV[0][srow * 72 + scol]     = vv0;
        *(uint4*)&sV[0][srow * 72 + scol + 8] = vv1;
    }
    __syncthreads();

    int cur = 0;
    for (int k0 = 0; k0 < SEQ; k0 += 64) {
        // Issue next tile's global loads first (hide L2 latency under compute).
        uint4 nkv0, nkv1, nvv0, nvv1;
        const bool has_next = (k0 + 64 < SEQ);
        if (has_next) {
            nkv0 = *(const uint4*)(Kst + (size_t)(k0 + 64) * DMODEL);
            nkv1 = *(const uint4*)(Kst + (size_t)(k0 + 64) * DMODEL + 8);
            nvv0 = *(const uint4*)(Vst + k0 + 64);
            nvv1 = *(const uint4*)(Vst + k0 + 64 + 8);
        }

        // --- QK^T from sK[cur] ---
        f32x4 s[2][4] = {};
#pragma unroll
        for (int nt = 0; nt < 4; nt++) {
            bf16x8 b0 = *(const bf16x8*)&sK[cur][(nt * 16 + l15) * 72 + quad * 8];
            bf16x8 b1 = *(const bf16x8*)&sK[cur][(nt * 16 + l15) * 72 + 32 + quad * 8];
#pragma unroll
            for (int m = 0; m < 2; m++) {
                s[m][nt] = __builtin_amdgcn_mfma_f32_16x16x32_bf16(qf[m][0], b0, s[m][nt], 0, 0, 0);
                s[m][nt] = __builtin_amdgcn_mfma_f32_16x16x32_bf16(qf[m][1], b1, s[m][nt], 0, 0, 0);
            }
        }

        // --- softmax numerator -> per-wave P tile ---
#pragma unroll
        for (int m = 0; m < 2; m++)
#pragma unroll
            for (int nt = 0; nt < 4; nt++) {
                float p0 = fast_exp2(s[m][nt][0]);
                float p1 = fast_exp2(s[m][nt][1]);
                float p2 = fast_exp2(s[m][nt][2]);
                float p3 = fast_exp2(s[m][nt][3]);
                l_part[m][0] += p0; l_part[m][1] += p1;
                l_part[m][2] += p2; l_part[m][3] += p3;
                unsigned int u01 = pk_bf16(p0, p1);
                unsigned int u23 = pk_bf16(p2, p3);
                const int rb   = m * 16 + quad * 4;
                const int colo = nt * 16 + l15;
                sPw[(rb + 0) * PST + colo] = (u16)(u01 & 0xFFFFu);
                sPw[(rb + 1) * PST + colo] = (u16)(u01 >> 16);
                sPw[(rb + 2) * PST + colo] = (u16)(u23 & 0xFFFFu);
                sPw[(rb + 3) * PST + colo] = (u16)(u23 >> 16);
            }

        // --- PV from sV[cur] (P is per-wave: no barrier needed) ---
#pragma unroll
        for (int c = 0; c < 2; c++) {
            bf16x8 pf0 = *(const bf16x8*)&sPw[(0 * 16 + l15) * PST + c * 32 + quad * 8];
            bf16x8 pf1 = *(const bf16x8*)&sPw[(1 * 16 + l15) * PST + c * 32 + quad * 8];
#pragma unroll
            for (int nt = 0; nt < 4; nt++) {
                bf16x8 vf = *(const bf16x8*)&sV[cur][(nt * 16 + l15) * 72 + c * 32 + quad * 8];
                oacc[0][nt] = __builtin_amdgcn_mfma_f32_16x16x32_bf16(pf0, vf, oacc[0][nt], 0, 0, 0);
                oacc[1][nt] = __builtin_amdgcn_mfma_f32_16x16x32_bf16(pf1, vf, oacc[1][nt], 0, 0, 0);
            }
        }

        // --- stage next tile into the other buffer; single barrier ---
        if (has_next) {
            const int nxt = cur ^ 1;
            *(uint4*)&sK[nxt][srow * 72 + scol]     = nkv0;
            *(uint4*)&sK[nxt][srow * 72 + scol + 8] = nkv1;
            *(uint4*)&sV[nxt][srow * 72 + scol]     = nvv0;
            *(uint4*)&sV[nxt][srow * 72 + scol + 8] = nvv1;
        }
        __syncthreads();
        cur ^= 1;
    }

#pragma unroll
    for (int m = 0; m < 2; m++) {
        float l_i[4];
#pragma unroll
        for (int r = 0; r < 4; r++) {
            float l = l_part[m][r];
            l += __shfl_xor(l, 1);
            l += __shfl_xor(l, 2);
            l += __shfl_xor(l, 4);
            l += __shfl_xor(l, 8);
            l_i[r] = l;
        }
#pragma unroll
        for (int nt = 0; nt < 4; nt++) {
            int col = head * DK + nt * 16 + l15;
#pragma unroll
            for (int r = 0; r < 4; r++) {
                int row = q0 + wave * 32 + m * 16 + quad * 4 + r;
                float o = oacc[m][nt][r] / l_i[r];
                u16 h = f2bf(o);
                AOh[(size_t)row * DMODEL + col] = h;
                AOl[(size_t)row * DMODEL + col] = f2bf(o - bf2f(h));
            }
        }
    }
}

// ---------------------------------------------------------------------------
extern "C" void kernel_launch(void* const* d_in, const int* in_sizes, int n_in,
                              void* d_out, int out_size, void* d_ws, size_t ws_size,
                              hipStream_t stream) {
    const float* query = (const float*)d_in[0];
    const float* key_t = (const float*)d_in[1];
    const float* value = (const float*)d_in[2];
    const float* wq    = (const float*)d_in[3];
    const float* wk    = (const float*)d_in[4];
    const float* wv    = (const float*)d_in[5];
    const float* wo    = (const float*)d_in[6];
    float* out = (float*)d_out;

    const size_t ACT_N = (size_t)SEQ * DMODEL;
    const size_t W_N   = (size_t)DMODEL * DMODEL;
    const size_t NEED  = 4 * ACT_N * sizeof(float);   // 64 MB (verified available)

    if (d_ws == nullptr || ws_size < NEED) {
        fallback_marker<<<dim3((out_size + 255) / 256), dim3(256), 0, stream>>>(out, out_size);
        return;
    }

    u16* ACT_HI = (u16*)d_ws;          // 8 MB  (phased)
    u16* ACT_LO = ACT_HI + ACT_N;      // 8 MB
    u16* W_HI   = ACT_LO + ACT_N;      // 2 MB  (phased)
    u16* W_LO   = W_HI + W_N;          // 2 MB
    u16* Qb     = W_LO + W_N;          // 8 MB  bf16 Q (pre-scaled 1/8*log2e)
    u16* Kb     = Qb + ACT_N;          // 8 MB  bf16 K
    u16* Vt     = Kb + ACT_N;          // 8 MB  bf16 V^T [DMODEL][SEQ]
    u16* AO_HI  = Vt + ACT_N;          // 8 MB
    u16* AO_LO  = AO_HI + ACT_N;       // 8 MB

    const int ACT4 = (int)(ACT_N / 4);
    const int W4   = (int)(W_N / 4);
    dim3 blk(256);
    dim3 pairg((ACT4 + 255) / 256, 2);
    dim3 wg((W4 + 255) / 256);

    const float QSCALE = 0.125f * 1.44269504f;   // 1/sqrt(dk) * log2(e)

    split_pair<<<pairg, blk, 0, stream>>>(query, ACT_HI, ACT_LO, ACT4, wq, W_HI, W_LO, W4);
    proj_hl_bf<<<dim3(SEQ / 128, DMODEL / 64), blk, 0, stream>>>(
        ACT_HI, ACT_LO, W_HI, W_LO, Qb, DMODEL, QSCALE);

    split_pair<<<pairg, blk, 0, stream>>>(key_t, ACT_HI, ACT_LO, ACT4, wk, W_HI, W_LO, W4);
    proj_hl_bf<<<dim3(SEQ / 128, DMODEL / 64), blk, 0, stream>>>(
        ACT_HI, ACT_LO, W_HI, W_LO, Kb, DMODEL, 1.0f);

    split_pair<<<pairg, blk, 0, stream>>>(value, ACT_HI, ACT_LO, ACT4, wv, W_HI, W_LO, W4);
    proj_hl_bf<<<dim3(DMODEL / 128, SEQ / 64), blk, 0, stream>>>(
        W_HI, W_LO, ACT_HI, ACT_LO, Vt, SEQ, 1.0f);

    attn_mfma<<<dim3(SEQ / 128, NHEAD), blk, 0, stream>>>(Qb, Kb, Vt, AO_HI, AO_LO);

    split_kernel<<<wg, blk, 0, stream>>>(wo, W_HI, W_LO, W4);
    proj_hl_f32<<<dim3(SEQ / 128, DMODEL / 64), blk, 0, stream>>>(
        AO_HI, AO_LO, W_HI, W_LO, out);
}

// Round 7
// 350.331 us; speedup vs baseline: 1.1715x; 1.1689x over previous
//
#include <hip/hip_runtime.h>
#include <hip/hip_bf16.h>
#include <cstdint>
#include <math.h>

#define DMODEL 1024
#define SEQ    4096
#define NHEAD  16
#define DK     64

typedef __attribute__((ext_vector_type(8))) short bf16x8;   // 8 bf16 = 4 VGPRs
typedef __attribute__((ext_vector_type(4))) float f32x4;
typedef unsigned short u16;

__device__ __forceinline__ u16 f2bf(float f) {
    union { float f; unsigned int u; } v; v.f = f;
    unsigned int u = v.u;
    u += 0x7FFFu + ((u >> 16) & 1u);   // round-to-nearest-even
    return (u16)(u >> 16);
}
__device__ __forceinline__ float bf2f(u16 h) {
    union { unsigned int u; float f; } v; v.u = ((unsigned int)h) << 16;
    return v.f;
}
__device__ __forceinline__ unsigned int pk_bf16(float a, float b) {
    union { __hip_bfloat162 h; unsigned int u; } v;
    v.h = __float22bfloat162_rn(make_float2(a, b));
    return v.u;
}
// raw v_exp_f32 = 2^x (Q is pre-scaled by 1/8 * log2(e) so this computes e^s)
__device__ __forceinline__ float fast_exp2(float x) {
    float r; asm("v_exp_f32 %0, %1" : "=v"(r) : "v"(x)); return r;
}

// Fallback marker if ws_size too small (diagnostic).
__global__ __launch_bounds__(256) void fallback_marker(float* __restrict__ out, int n) {
    int i = blockIdx.x * 256 + threadIdx.x;
    if (i < n) out[i] = (i == 0) ? 12345.0f : 0.0f;
}

// ---------------------------------------------------------------------------
// fp32 -> (hi, lo) bf16 split, elementwise (float4 granularity).
// ---------------------------------------------------------------------------
__device__ __forceinline__ void split4_store(const float* __restrict__ in,
                                             u16* __restrict__ hi,
                                             u16* __restrict__ lo, int i) {
    float4 v = ((const float4*)in)[i];
    u16 h0 = f2bf(v.x), h1 = f2bf(v.y), h2 = f2bf(v.z), h3 = f2bf(v.w);
    ushort4 hv; hv.x = h0; hv.y = h1; hv.z = h2; hv.w = h3;
    ushort4 lv;
    lv.x = f2bf(v.x - bf2f(h0)); lv.y = f2bf(v.y - bf2f(h1));
    lv.z = f2bf(v.z - bf2f(h2)); lv.w = f2bf(v.w - bf2f(h3));
    ((ushort4*)hi)[i] = hv;
    ((ushort4*)lo)[i] = lv;
}

__global__ __launch_bounds__(256) void split_kernel(const float* __restrict__ in,
                                                    u16* __restrict__ hi,
                                                    u16* __restrict__ lo, int n4) {
    int i = blockIdx.x * 256 + threadIdx.x;
    if (i < n4) split4_store(in, hi, lo, i);
}

// Activation (y=0) + weight (y=1) split fused into one launch.
__global__ __launch_bounds__(256) void split_pair(const float* __restrict__ a_in,
                                                  u16* __restrict__ a_hi,
                                                  u16* __restrict__ a_lo, int a_n4,
                                                  const float* __restrict__ w_in,
                                                  u16* __restrict__ w_hi,
                                                  u16* __restrict__ w_lo, int w_n4) {
    int i = blockIdx.x * 256 + threadIdx.x;
    if (blockIdx.y == 0) {
        if (i < a_n4) split4_store(a_in, a_hi, a_lo, i);
    } else {
        if (i < w_n4) split4_store(w_in, w_hi, w_lo, i);
    }
}

// ---------------------------------------------------------------------------
// hi/lo-split MFMA GEMM core v2 (round-0/2 PROVEN, 256 threads): 128x64
// tile, wave owns 32 rows (2 m-frags) x 64 cols. Per-output accumulation
// order fixed. (r4: 512-thread variant slower; r6: gload_lds variant slower.)
// ---------------------------------------------------------------------------
__device__ __forceinline__ void gemm_core_hl2(const u16* __restrict__ aHi,
                                              const u16* __restrict__ aLo,
                                              const u16* __restrict__ bHi,
                                              const u16* __restrict__ bLo,
                                              int bm, int bn,
                                              f32x4 (&acc)[2][4]) {
    __shared__ u16 sAh[128 * 72], sAl[128 * 72];   // 18 KB each
    __shared__ u16 sBh[64 * 72],  sBl[64 * 72];    // 9 KB each  (54 KB total)

    const int tid  = threadIdx.x;
    const int wave = tid >> 6;
    const int lane = tid & 63;
    const int quad = lane >> 4;
    const int l15  = lane & 15;
    const int srow = tid >> 2;          // 0..63
    const int scol = (tid & 3) * 16;    // 0,16,32,48

    const u16* pAh0 = aHi + (size_t)(bm + srow) * DMODEL + scol;
    const u16* pAh1 = aHi + (size_t)(bm + 64 + srow) * DMODEL + scol;
    const u16* pAl0 = aLo + (size_t)(bm + srow) * DMODEL + scol;
    const u16* pAl1 = aLo + (size_t)(bm + 64 + srow) * DMODEL + scol;
    const u16* pBh  = bHi + (size_t)(bn + srow) * DMODEL + scol;
    const u16* pBl  = bLo + (size_t)(bn + srow) * DMODEL + scol;

    for (int k0 = 0; k0 < DMODEL; k0 += 64) {
        uint4 ah00 = *(const uint4*)(pAh0 + k0);
        uint4 ah01 = *(const uint4*)(pAh0 + k0 + 8);
        uint4 ah10 = *(const uint4*)(pAh1 + k0);
        uint4 ah11 = *(const uint4*)(pAh1 + k0 + 8);
        uint4 al00 = *(const uint4*)(pAl0 + k0);
        uint4 al01 = *(const uint4*)(pAl0 + k0 + 8);
        uint4 al10 = *(const uint4*)(pAl1 + k0);
        uint4 al11 = *(const uint4*)(pAl1 + k0 + 8);
        uint4 bh0  = *(const uint4*)(pBh + k0);
        uint4 bh1  = *(const uint4*)(pBh + k0 + 8);
        uint4 bl0  = *(const uint4*)(pBl + k0);
        uint4 bl1  = *(const uint4*)(pBl + k0 + 8);

        __syncthreads();
        *(uint4*)&sAh[srow * 72 + scol]            = ah00;
        *(uint4*)&sAh[srow * 72 + scol + 8]        = ah01;
        *(uint4*)&sAh[(64 + srow) * 72 + scol]     = ah10;
        *(uint4*)&sAh[(64 + srow) * 72 + scol + 8] = ah11;
        *(uint4*)&sAl[srow * 72 + scol]            = al00;
        *(uint4*)&sAl[srow * 72 + scol + 8]        = al01;
        *(uint4*)&sAl[(64 + srow) * 72 + scol]     = al10;
        *(uint4*)&sAl[(64 + srow) * 72 + scol + 8] = al11;
        *(uint4*)&sBh[srow * 72 + scol]            = bh0;
        *(uint4*)&sBh[srow * 72 + scol + 8]        = bh1;
        *(uint4*)&sBl[srow * 72 + scol]            = bl0;
        *(uint4*)&sBl[srow * 72 + scol + 8]        = bl1;
        __syncthreads();

#pragma unroll
        for (int c = 0; c < 2; c++) {
            bf16x8 ah[2], al[2];
#pragma unroll
            for (int m = 0; m < 2; m++) {
                const int aoff = (wave * 32 + m * 16 + l15) * 72 + c * 32 + quad * 8;
                ah[m] = *(const bf16x8*)&sAh[aoff];
                al[m] = *(const bf16x8*)&sAl[aoff];
            }
#pragma unroll
            for (int nt = 0; nt < 4; nt++) {
                const int boff = (nt * 16 + l15) * 72 + c * 32 + quad * 8;
                bf16x8 bhf = *(const bf16x8*)&sBh[boff];
                bf16x8 blf = *(const bf16x8*)&sBl[boff];
#pragma unroll
                for (int m = 0; m < 2; m++) {
                    acc[m][nt] = __builtin_amdgcn_mfma_f32_16x16x32_bf16(ah[m], bhf, acc[m][nt], 0, 0, 0);
                    acc[m][nt] = __builtin_amdgcn_mfma_f32_16x16x32_bf16(ah[m], blf, acc[m][nt], 0, 0, 0);
                    acc[m][nt] = __builtin_amdgcn_mfma_f32_16x16x32_bf16(al[m], bhf, acc[m][nt], 0, 0, 0);
                }
            }
        }
    }
}

__global__ __launch_bounds__(256) void proj_hl_bf(const u16* __restrict__ aHi,
                                                  const u16* __restrict__ aLo,
                                                  const u16* __restrict__ bHi,
                                                  const u16* __restrict__ bLo,
                                                  u16* __restrict__ C,
                                                  int ldc, float scale) {
    const int bm = blockIdx.x * 128;
    const int bn = blockIdx.y * 64;
    f32x4 acc[2][4] = {};
    gemm_core_hl2(aHi, aLo, bHi, bLo, bm, bn, acc);
    const int lane = threadIdx.x & 63;
    const int wave = threadIdx.x >> 6;
    const int quad = lane >> 4;
    const int l15  = lane & 15;
#pragma unroll
    for (int m = 0; m < 2; m++)
#pragma unroll
        for (int nt = 0; nt < 4; nt++) {
            int col = bn + nt * 16 + l15;
#pragma unroll
            for (int r = 0; r < 4; r++) {
                int row = bm + wave * 32 + m * 16 + quad * 4 + r;
                C[(size_t)row * ldc + col] = f2bf(acc[m][nt][r] * scale);
            }
        }
}

__global__ __launch_bounds__(256) void proj_hl_f32(const u16* __restrict__ aHi,
                                                   const u16* __restrict__ aLo,
                                                   const u16* __restrict__ bHi,
                                                   const u16* __restrict__ bLo,
                                                   float* __restrict__ C) {
    const int bm = blockIdx.x * 128;
    const int bn = blockIdx.y * 64;
    f32x4 acc[2][4] = {};
    gemm_core_hl2(aHi, aLo, bHi, bLo, bm, bn, acc);
    const int lane = threadIdx.x & 63;
    const int wave = threadIdx.x >> 6;
    const int quad = lane >> 4;
    const int l15  = lane & 15;
#pragma unroll
    for (int m = 0; m < 2; m++)
#pragma unroll
        for (int nt = 0; nt < 4; nt++) {
            int col = bn + nt * 16 + l15;
#pragma unroll
            for (int r = 0; r < 4; r++) {
                int row = bm + wave * 32 + m * 16 + quad * 4 + r;
                C[(size_t)row * DMODEL + col] = acc[m][nt][r];
            }
        }
}

// ---------------------------------------------------------------------------
// MFMA flash attention v7 (SWAPPED QK^T): same structure as proven r2 v4
// (256 thr, wave owns 32 q-rows, dbuf K/V, single barrier, XCD swizzle),
// but QK^T computed as mfma(K_frag, Q_frag) -> P lands TRANSPOSED in lanes:
// lane (l15,quad) holds P[key=nt*16+quad*4+r][q=m*16+l15]. The P-store is
// then ONE aligned ds_write_b64 per (m,nt) (8/kstep vs 32 scalar b16),
// written directly in the [q][key] layout the (unchanged) PV reads consume.
// l-sum becomes per-lane + shfl_xor(16,32) + epilogue redistribute.
// PV MFMA sequence and P bf16 values bit-identical to r2; l reassociated.
// ---------------------------------------------------------------------------
#define PST 72   // sP row stride (u16); rows 16B-aligned for b128 reads

__global__ __launch_bounds__(256) void attn_mfma(const u16* __restrict__ Q,
                                                 const u16* __restrict__ K,
                                                 const u16* __restrict__ Vt,
                                                 u16* __restrict__ AOh,
                                                 u16* __restrict__ AOl) {
    __shared__ u16 sK[2][64 * 72];       // K tile [key][d]   9 KB x2
    __shared__ u16 sV[2][64 * 72];       // V tile [d][key]   9 KB x2
    __shared__ u16 sP[4 * 32 * PST];     // per-wave P [32 q][64 key] 18 KB

    // XCD-aware bijective swizzle: grid (32,16) = 512 blocks, chunk = 64.
    const int lin  = blockIdx.y * gridDim.x + blockIdx.x;
    const int swz  = (lin & 7) * 64 + (lin >> 3);
    const int head = swz >> 5;           // 0..15; 2 whole heads per XCD
    const int q0   = (swz & 31) * 128;

    const int tid  = threadIdx.x;
    const int wave = tid >> 6;
    const int lane = tid & 63;
    const int quad = lane >> 4;
    const int l15  = lane & 15;
    const int srow = tid >> 2;           // 0..63
    const int scol = (tid & 3) * 16;     // 0,16,32,48

    bf16x8 qf[2][2];
#pragma unroll
    for (int m = 0; m < 2; m++) {
        const u16* qb = Q + (size_t)(q0 + wave * 32 + m * 16 + l15) * DMODEL + head * DK;
        qf[m][0] = *(const bf16x8*)(qb + quad * 8);
        qf[m][1] = *(const bf16x8*)(qb + 32 + quad * 8);
    }

    f32x4 oacc[2][4] = {};
    float l_part[2] = {0.0f, 0.0f};      // per-lane: q = m*16 + l15, 16 keys

    const u16* Kst = K  + (size_t)srow * DMODEL + head * DK + scol;
    const u16* Vst = Vt + (size_t)(head * DK + srow) * SEQ + scol;
    u16* sPw = sP + wave * 32 * PST;

    // Prologue: stage tile 0 into buffer 0.
    {
        uint4 kv0 = *(const uint4*)(Kst);
        uint4 kv1 = *(const uint4*)(Kst + 8);
        uint4 vv0 = *(const uint4*)(Vst);
        uint4 vv1 = *(const uint4*)(Vst + 8);
        *(uint4*)&sK[0][srow * 72 + scol]     = kv0;
        *(uint4*)&sK[0][srow * 72 + scol + 8] = kv1;
        *(uint4*)&sV[0][srow * 72 + scol]     = vv0;
        *(uint4*)&sV[0][srow * 72 + scol + 8] = vv1;
    }
    __syncthreads();

    int cur = 0;
    for (int k0 = 0; k0 < SEQ; k0 += 64) {
        // Issue next tile's global loads first (hide L2 latency under compute).
        uint4 nkv0, nkv1, nvv0, nvv1;
        const bool has_next = (k0 + 64 < SEQ);
        if (has_next) {
            nkv0 = *(const uint4*)(Kst + (size_t)(k0 + 64) * DMODEL);
            nkv1 = *(const uint4*)(Kst + (size_t)(k0 + 64) * DMODEL + 8);
            nvv0 = *(const uint4*)(Vst + k0 + 64);
            nvv1 = *(const uint4*)(Vst + k0 + 64 + 8);
        }

        // --- QK^T SWAPPED: s[nt][m] = K_frag * Q_frag  (fragments unchanged)
        // D[row=key(nt*16+quad*4+r)][col=q(m*16+l15)]
        f32x4 s[4][2] = {};
#pragma unroll
        for (int nt = 0; nt < 4; nt++) {
            bf16x8 kf0 = *(const bf16x8*)&sK[cur][(nt * 16 + l15) * 72 + quad * 8];
            bf16x8 kf1 = *(const bf16x8*)&sK[cur][(nt * 16 + l15) * 72 + 32 + quad * 8];
#pragma unroll
            for (int m = 0; m < 2; m++) {
                s[nt][m] = __builtin_amdgcn_mfma_f32_16x16x32_bf16(kf0, qf[m][0], s[nt][m], 0, 0, 0);
                s[nt][m] = __builtin_amdgcn_mfma_f32_16x16x32_bf16(kf1, qf[m][1], s[nt][m], 0, 0, 0);
            }
        }

        // --- softmax numerator: exp, accumulate l, ONE b64 store per (m,nt)
#pragma unroll
        for (int m = 0; m < 2; m++)
#pragma unroll
            for (int nt = 0; nt < 4; nt++) {
                float p0 = fast_exp2(s[nt][m][0]);
                float p1 = fast_exp2(s[nt][m][1]);
                float p2 = fast_exp2(s[nt][m][2]);
                float p3 = fast_exp2(s[nt][m][3]);
                l_part[m] += (p0 + p1) + (p2 + p3);
                uint2 w;
                w.x = pk_bf16(p0, p1);
                w.y = pk_bf16(p2, p3);
                // P[q = m*16+l15][key = nt*16 + quad*4 .. +3]
                *(uint2*)&sPw[(m * 16 + l15) * PST + nt * 16 + quad * 4] = w;
            }

        // --- PV from sV[cur] (UNCHANGED layout: P read as [q][key]) ---
#pragma unroll
        for (int c = 0; c < 2; c++) {
            bf16x8 pf0 = *(const bf16x8*)&sPw[(0 * 16 + l15) * PST + c * 32 + quad * 8];
            bf16x8 pf1 = *(const bf16x8*)&sPw[(1 * 16 + l15) * PST + c * 32 + quad * 8];
#pragma unroll
            for (int nt = 0; nt < 4; nt++) {
                bf16x8 vf = *(const bf16x8*)&sV[cur][(nt * 16 + l15) * 72 + c * 32 + quad * 8];
                oacc[0][nt] = __builtin_amdgcn_mfma_f32_16x16x32_bf16(pf0, vf, oacc[0][nt], 0, 0, 0);
                oacc[1][nt] = __builtin_amdgcn_mfma_f32_16x16x32_bf16(pf1, vf, oacc[1][nt], 0, 0, 0);
            }
        }

        // --- stage next tile into the other buffer; single barrier ---
        if (has_next) {
            const int nxt = cur ^ 1;
            *(uint4*)&sK[nxt][srow * 72 + scol]     = nkv0;
            *(uint4*)&sK[nxt][srow * 72 + scol + 8] = nkv1;
            *(uint4*)&sV[nxt][srow * 72 + scol]     = nvv0;
            *(uint4*)&sV[nxt][srow * 72 + scol + 8] = nvv1;
        }
        __syncthreads();
        cur ^= 1;
    }

    // l reduction: full sum over 64 keys/quad-groups, replicated per l15.
    float lf[2];
#pragma unroll
    for (int m = 0; m < 2; m++) {
        float l = l_part[m];
        l += __shfl_xor(l, 16);
        l += __shfl_xor(l, 32);
        lf[m] = l;                       // value at lane L = l for q=m*16+(L&15)
    }
#pragma unroll
    for (int m = 0; m < 2; m++) {
        float l_i[4];
#pragma unroll
        for (int r = 0; r < 4; r++)      // need q = m*16 + quad*4 + r
            l_i[r] = __shfl(lf[m], (lane & 48) | (quad * 4 + r));
#pragma unroll
        for (int nt = 0; nt < 4; nt++) {
            int col = head * DK + nt * 16 + l15;
#pragma unroll
            for (int r = 0; r < 4; r++) {
                int row = q0 + wave * 32 + m * 16 + quad * 4 + r;
                float o = oacc[m][nt][r] / l_i[r];
                u16 h = f2bf(o);
                AOh[(size_t)row * DMODEL + col] = h;
                AOl[(size_t)row * DMODEL + col] = f2bf(o - bf2f(h));
            }
        }
    }
}

// ---------------------------------------------------------------------------
extern "C" void kernel_launch(void* const* d_in, const int* in_sizes, int n_in,
                              void* d_out, int out_size, void* d_ws, size_t ws_size,
                              hipStream_t stream) {
    const float* query = (const float*)d_in[0];
    const float* key_t = (const float*)d_in[1];
    const float* value = (const float*)d_in[2];
    const float* wq    = (const float*)d_in[3];
    const float* wk    = (const float*)d_in[4];
    const float* wv    = (const float*)d_in[5];
    const float* wo    = (const float*)d_in[6];
    float* out = (float*)d_out;

    const size_t ACT_N = (size_t)SEQ * DMODEL;
    const size_t W_N   = (size_t)DMODEL * DMODEL;
    const size_t NEED  = 4 * ACT_N * sizeof(float);   // 64 MB (verified available)

    if (d_ws == nullptr || ws_size < NEED) {
        fallback_marker<<<dim3((out_size + 255) / 256), dim3(256), 0, stream>>>(out, out_size);
        return;
    }

    u16* ACT_HI = (u16*)d_ws;          // 8 MB  (phased)
    u16* ACT_LO = ACT_HI + ACT_N;      // 8 MB
    u16* W_HI   = ACT_LO + ACT_N;      // 2 MB  (phased)
    u16* W_LO   = W_HI + W_N;          // 2 MB
    u16* Qb     = W_LO + W_N;          // 8 MB  bf16 Q (pre-scaled 1/8*log2e)
    u16* Kb     = Qb + ACT_N;          // 8 MB  bf16 K
    u16* Vt     = Kb + ACT_N;          // 8 MB  bf16 V^T [DMODEL][SEQ]
    u16* AO_HI  = Vt + ACT_N;          // 8 MB
    u16* AO_LO  = AO_HI + ACT_N;       // 8 MB

    const int ACT4 = (int)(ACT_N / 4);
    const int W4   = (int)(W_N / 4);
    dim3 blk(256);
    dim3 pairg((ACT4 + 255) / 256, 2);
    dim3 wg((W4 + 255) / 256);

    const float QSCALE = 0.125f * 1.44269504f;   // 1/sqrt(dk) * log2(e)

    split_pair<<<pairg, blk, 0, stream>>>(query, ACT_HI, ACT_LO, ACT4, wq, W_HI, W_LO, W4);
    proj_hl_bf<<<dim3(SEQ / 128, DMODEL / 64), blk, 0, stream>>>(
        ACT_HI, ACT_LO, W_HI, W_LO, Qb, DMODEL, QSCALE);

    split_pair<<<pairg, blk, 0, stream>>>(key_t, ACT_HI, ACT_LO, ACT4, wk, W_HI, W_LO, W4);
    proj_hl_bf<<<dim3(SEQ / 128, DMODEL / 64), blk, 0, stream>>>(
        ACT_HI, ACT_LO, W_HI, W_LO, Kb, DMODEL, 1.0f);

    split_pair<<<pairg, blk, 0, stream>>>(value, ACT_HI, ACT_LO, ACT4, wv, W_HI, W_LO, W4);
    proj_hl_bf<<<dim3(DMODEL / 128, SEQ / 64), blk, 0, stream>>>(
        W_HI, W_LO, ACT_HI, ACT_LO, Vt, SEQ, 1.0f);

    attn_mfma<<<dim3(SEQ / 128, NHEAD), blk, 0, stream>>>(Qb, Kb, Vt, AO_HI, AO_LO);

    split_kernel<<<wg, blk, 0, stream>>>(wo, W_HI, W_LO, W4);
    proj_hl_f32<<<dim3(SEQ / 128, DMODEL / 64), blk, 0, stream>>>(
        AO_HI, AO_LO, W_HI, W_LO, out);
}

// Round 8
// 334.915 us; speedup vs baseline: 1.2254x; 1.0460x over previous
//
#include <hip/hip_runtime.h>
#include <hip/hip_bf16.h>
#include <hip/hip_fp16.h>
#include <cstdint>
#include <math.h>

#define DMODEL 1024
#define SEQ    4096
#define NHEAD  16
#define DK     64

typedef __attribute__((ext_vector_type(8))) short bf16x8;       // 8 bf16 = 4 VGPRs
typedef __attribute__((ext_vector_type(8))) _Float16 f16x8;     // 8 fp16 = 4 VGPRs
typedef __attribute__((ext_vector_type(4))) float f32x4;
typedef unsigned short u16;

__device__ __forceinline__ u16 f2bf(float f) {
    union { float f; unsigned int u; } v; v.f = f;
    unsigned int u = v.u;
    u += 0x7FFFu + ((u >> 16) & 1u);   // round-to-nearest-even
    return (u16)(u >> 16);
}
__device__ __forceinline__ float bf2f(u16 h) {
    union { unsigned int u; float f; } v; v.u = ((unsigned int)h) << 16;
    return v.f;
}
__device__ __forceinline__ u16 f2h(float f) {
    __half h = __float2half_rn(f);
    union { __half h; u16 u; } v; v.h = h; return v.u;
}
__device__ __forceinline__ float h2f(u16 x) {
    union { u16 u; __half h; } v; v.u = x;
    return __half2float(v.h);
}
__device__ __forceinline__ unsigned int pk_bf16(float a, float b) {
    union { __hip_bfloat162 h; unsigned int u; } v;
    v.h = __float22bfloat162_rn(make_float2(a, b));
    return v.u;
}
// raw v_exp_f32 = 2^x (Q is pre-scaled by 1/8 * log2(e) so this computes e^s)
__device__ __forceinline__ float fast_exp2(float x) {
    float r; asm("v_exp_f32 %0, %1" : "=v"(r) : "v"(x)); return r;
}

// Fallback marker if ws_size too small (diagnostic).
__global__ __launch_bounds__(256) void fallback_marker(float* __restrict__ out, int n) {
    int i = blockIdx.x * 256 + threadIdx.x;
    if (i < n) out[i] = (i == 0) ? 12345.0f : 0.0f;
}

// ---------------------------------------------------------------------------
// fp32 -> (hi, lo) FP16 split, elementwise (float4 granularity).
// fp16 hi carries 11 mantissa bits; hi+lo ~22 bits (vs bf16 pair's 16).
// ---------------------------------------------------------------------------
__device__ __forceinline__ void split4_store(const float* __restrict__ in,
                                             u16* __restrict__ hi,
                                             u16* __restrict__ lo, int i) {
    float4 v = ((const float4*)in)[i];
    u16 h0 = f2h(v.x), h1 = f2h(v.y), h2 = f2h(v.z), h3 = f2h(v.w);
    ushort4 hv; hv.x = h0; hv.y = h1; hv.z = h2; hv.w = h3;
    ushort4 lv;
    lv.x = f2h(v.x - h2f(h0)); lv.y = f2h(v.y - h2f(h1));
    lv.z = f2h(v.z - h2f(h2)); lv.w = f2h(v.w - h2f(h3));
    ((ushort4*)hi)[i] = hv;
    ((ushort4*)lo)[i] = lv;
}

__global__ __launch_bounds__(256) void split_kernel(const float* __restrict__ in,
                                                    u16* __restrict__ hi,
                                                    u16* __restrict__ lo, int n4) {
    int i = blockIdx.x * 256 + threadIdx.x;
    if (i < n4) split4_store(in, hi, lo, i);
}

// Activation (y=0) + weight (y=1) split fused into one launch.
__global__ __launch_bounds__(256) void split_pair(const float* __restrict__ a_in,
                                                  u16* __restrict__ a_hi,
                                                  u16* __restrict__ a_lo, int a_n4,
                                                  const float* __restrict__ w_in,
                                                  u16* __restrict__ w_hi,
                                                  u16* __restrict__ w_lo, int w_n4) {
    int i = blockIdx.x * 256 + threadIdx.x;
    if (blockIdx.y == 0) {
        if (i < a_n4) split4_store(a_in, a_hi, a_lo, i);
    } else {
        if (i < w_n4) split4_store(w_in, w_hi, w_lo, i);
    }
}

// ---------------------------------------------------------------------------
// FP16 2-term MFMA GEMM core v6: C = (Ah+Al) * Bh  (drops A*Bl; fp16 lo is
// 2^-11 so the dropped term's std ~ 2.8e-4 per output, well under budget).
// Same 128x64 tile / 256 thr / 2-barrier loop as the proven v2, but:
// MFMA 48->32 per kstep, DS ops 36->26, LDS 54->45 KB (no sBl).
// Per-output accumulation order fixed (hh then lh, k ascending).
// ---------------------------------------------------------------------------
__device__ __forceinline__ void gemm_core_fp16(const u16* __restrict__ aHi,
                                               const u16* __restrict__ aLo,
                                               const u16* __restrict__ bHi,
                                               int bm, int bn,
                                               f32x4 (&acc)[2][4]) {
    __shared__ u16 sAh[128 * 72], sAl[128 * 72];   // 18 KB each
    __shared__ u16 sBh[64 * 72];                   // 9 KB      (45 KB total)

    const int tid  = threadIdx.x;
    const int wave = tid >> 6;
    const int lane = tid & 63;
    const int quad = lane >> 4;
    const int l15  = lane & 15;
    const int srow = tid >> 2;          // 0..63
    const int scol = (tid & 3) * 16;    // 0,16,32,48

    const u16* pAh0 = aHi + (size_t)(bm + srow) * DMODEL + scol;
    const u16* pAh1 = aHi + (size_t)(bm + 64 + srow) * DMODEL + scol;
    const u16* pAl0 = aLo + (size_t)(bm + srow) * DMODEL + scol;
    const u16* pAl1 = aLo + (size_t)(bm + 64 + srow) * DMODEL + scol;
    const u16* pBh  = bHi + (size_t)(bn + srow) * DMODEL + scol;

    for (int k0 = 0; k0 < DMODEL; k0 += 64) {
        uint4 ah00 = *(const uint4*)(pAh0 + k0);
        uint4 ah01 = *(const uint4*)(pAh0 + k0 + 8);
        uint4 ah10 = *(const uint4*)(pAh1 + k0);
        uint4 ah11 = *(const uint4*)(pAh1 + k0 + 8);
        uint4 al00 = *(const uint4*)(pAl0 + k0);
        uint4 al01 = *(const uint4*)(pAl0 + k0 + 8);
        uint4 al10 = *(const uint4*)(pAl1 + k0);
        uint4 al11 = *(const uint4*)(pAl1 + k0 + 8);
        uint4 bh0  = *(const uint4*)(pBh + k0);
        uint4 bh1  = *(const uint4*)(pBh + k0 + 8);

        __syncthreads();
        *(uint4*)&sAh[srow * 72 + scol]            = ah00;
        *(uint4*)&sAh[srow * 72 + scol + 8]        = ah01;
        *(uint4*)&sAh[(64 + srow) * 72 + scol]     = ah10;
        *(uint4*)&sAh[(64 + srow) * 72 + scol + 8] = ah11;
        *(uint4*)&sAl[srow * 72 + scol]            = al00;
        *(uint4*)&sAl[srow * 72 + scol + 8]        = al01;
        *(uint4*)&sAl[(64 + srow) * 72 + scol]     = al10;
        *(uint4*)&sAl[(64 + srow) * 72 + scol + 8] = al11;
        *(uint4*)&sBh[srow * 72 + scol]            = bh0;
        *(uint4*)&sBh[srow * 72 + scol + 8]        = bh1;
        __syncthreads();

#pragma unroll
        for (int c = 0; c < 2; c++) {
            f16x8 ah[2], al[2];
#pragma unroll
            for (int m = 0; m < 2; m++) {
                const int aoff = (wave * 32 + m * 16 + l15) * 72 + c * 32 + quad * 8;
                ah[m] = *(const f16x8*)&sAh[aoff];
                al[m] = *(const f16x8*)&sAl[aoff];
            }
#pragma unroll
            for (int nt = 0; nt < 4; nt++) {
                const int boff = (nt * 16 + l15) * 72 + c * 32 + quad * 8;
                f16x8 bhf = *(const f16x8*)&sBh[boff];
#pragma unroll
                for (int m = 0; m < 2; m++) {
                    acc[m][nt] = __builtin_amdgcn_mfma_f32_16x16x32_f16(ah[m], bhf, acc[m][nt], 0, 0, 0);
                    acc[m][nt] = __builtin_amdgcn_mfma_f32_16x16x32_f16(al[m], bhf, acc[m][nt], 0, 0, 0);
                }
            }
        }
    }
}

__global__ __launch_bounds__(256) void proj_hl_bf(const u16* __restrict__ aHi,
                                                  const u16* __restrict__ aLo,
                                                  const u16* __restrict__ bHi,
                                                  u16* __restrict__ C,
                                                  int ldc, float scale) {
    const int bm = blockIdx.x * 128;
    const int bn = blockIdx.y * 64;
    f32x4 acc[2][4] = {};
    gemm_core_fp16(aHi, aLo, bHi, bm, bn, acc);
    const int lane = threadIdx.x & 63;
    const int wave = threadIdx.x >> 6;
    const int quad = lane >> 4;
    const int l15  = lane & 15;
#pragma unroll
    for (int m = 0; m < 2; m++)
#pragma unroll
        for (int nt = 0; nt < 4; nt++) {
            int col = bn + nt * 16 + l15;
#pragma unroll
            for (int r = 0; r < 4; r++) {
                int row = bm + wave * 32 + m * 16 + quad * 4 + r;
                C[(size_t)row * ldc + col] = f2bf(acc[m][nt][r] * scale);
            }
        }
}

__global__ __launch_bounds__(256) void proj_hl_f32(const u16* __restrict__ aHi,
                                                   const u16* __restrict__ aLo,
                                                   const u16* __restrict__ bHi,
                                                   float* __restrict__ C) {
    const int bm = blockIdx.x * 128;
    const int bn = blockIdx.y * 64;
    f32x4 acc[2][4] = {};
    gemm_core_fp16(aHi, aLo, bHi, bm, bn, acc);
    const int lane = threadIdx.x & 63;
    const int wave = threadIdx.x >> 6;
    const int quad = lane >> 4;
    const int l15  = lane & 15;
#pragma unroll
    for (int m = 0; m < 2; m++)
#pragma unroll
        for (int nt = 0; nt < 4; nt++) {
            int col = bn + nt * 16 + l15;
#pragma unroll
            for (int r = 0; r < 4; r++) {
                int row = bm + wave * 32 + m * 16 + quad * 4 + r;
                C[(size_t)row * DMODEL + col] = acc[m][nt][r];
            }
        }
}

// ---------------------------------------------------------------------------
// MFMA flash attention v7 (round-7 PROVEN, swapped QK^T): 256 thr, wave owns
// 32 q-rows, dbuf K/V, single barrier, XCD swizzle. Internals bf16 (Qb/Kb/Vt
// unchanged); only the epilogue now writes AO as FP16 hi/lo for the fp16
// output projection (fp16 pair = ~22 mantissa bits > bf16 pair's 16).
// ---------------------------------------------------------------------------
#define PST 72   // sP row stride (u16); rows 16B-aligned for b128 reads

__global__ __launch_bounds__(256) void attn_mfma(const u16* __restrict__ Q,
                                                 const u16* __restrict__ K,
                                                 const u16* __restrict__ Vt,
                                                 u16* __restrict__ AOh,
                                                 u16* __restrict__ AOl) {
    __shared__ u16 sK[2][64 * 72];       // K tile [key][d]   9 KB x2
    __shared__ u16 sV[2][64 * 72];       // V tile [d][key]   9 KB x2
    __shared__ u16 sP[4 * 32 * PST];     // per-wave P [32 q][64 key] 18 KB

    // XCD-aware bijective swizzle: grid (32,16) = 512 blocks, chunk = 64.
    const int lin  = blockIdx.y * gridDim.x + blockIdx.x;
    const int swz  = (lin & 7) * 64 + (lin >> 3);
    const int head = swz >> 5;           // 0..15; 2 whole heads per XCD
    const int q0   = (swz & 31) * 128;

    const int tid  = threadIdx.x;
    const int wave = tid >> 6;
    const int lane = tid & 63;
    const int quad = lane >> 4;
    const int l15  = lane & 15;
    const int srow = tid >> 2;           // 0..63
    const int scol = (tid & 3) * 16;     // 0,16,32,48

    bf16x8 qf[2][2];
#pragma unroll
    for (int m = 0; m < 2; m++) {
        const u16* qb = Q + (size_t)(q0 + wave * 32 + m * 16 + l15) * DMODEL + head * DK;
        qf[m][0] = *(const bf16x8*)(qb + quad * 8);
        qf[m][1] = *(const bf16x8*)(qb + 32 + quad * 8);
    }

    f32x4 oacc[2][4] = {};
    float l_part[2] = {0.0f, 0.0f};      // per-lane: q = m*16 + l15, 16 keys

    const u16* Kst = K  + (size_t)srow * DMODEL + head * DK + scol;
    const u16* Vst = Vt + (size_t)(head * DK + srow) * SEQ + scol;
    u16* sPw = sP + wave * 32 * PST;

    // Prologue: stage tile 0 into buffer 0.
    {
        uint4 kv0 = *(const uint4*)(Kst);
        uint4 kv1 = *(const uint4*)(Kst + 8);
        uint4 vv0 = *(const uint4*)(Vst);
        uint4 vv1 = *(const uint4*)(Vst + 8);
        *(uint4*)&sK[0][srow * 72 + scol]     = kv0;
        *(uint4*)&sK[0][srow * 72 + scol + 8] = kv1;
        *(uint4*)&sV[0][srow * 72 + scol]     = vv0;
        *(uint4*)&sV[0][srow * 72 + scol + 8] = vv1;
    }
    __syncthreads();

    int cur = 0;
    for (int k0 = 0; k0 < SEQ; k0 += 64) {
        // Issue next tile's global loads first (hide L2 latency under compute).
        uint4 nkv0, nkv1, nvv0, nvv1;
        const bool has_next = (k0 + 64 < SEQ);
        if (has_next) {
            nkv0 = *(const uint4*)(Kst + (size_t)(k0 + 64) * DMODEL);
            nkv1 = *(const uint4*)(Kst + (size_t)(k0 + 64) * DMODEL + 8);
            nvv0 = *(const uint4*)(Vst + k0 + 64);
            nvv1 = *(const uint4*)(Vst + k0 + 64 + 8);
        }

        // --- QK^T SWAPPED: s[nt][m] = K_frag * Q_frag  (fragments unchanged)
        // D[row=key(nt*16+quad*4+r)][col=q(m*16+l15)]
        f32x4 s[4][2] = {};
#pragma unroll
        for (int nt = 0; nt < 4; nt++) {
            bf16x8 kf0 = *(const bf16x8*)&sK[cur][(nt * 16 + l15) * 72 + quad * 8];
            bf16x8 kf1 = *(const bf16x8*)&sK[cur][(nt * 16 + l15) * 72 + 32 + quad * 8];
#pragma unroll
            for (int m = 0; m < 2; m++) {
                s[nt][m] = __builtin_amdgcn_mfma_f32_16x16x32_bf16(kf0, qf[m][0], s[nt][m], 0, 0, 0);
                s[nt][m] = __builtin_amdgcn_mfma_f32_16x16x32_bf16(kf1, qf[m][1], s[nt][m], 0, 0, 0);
            }
        }

        // --- softmax numerator: exp, accumulate l, ONE b64 store per (m,nt)
#pragma unroll
        for (int m = 0; m < 2; m++)
#pragma unroll
            for (int nt = 0; nt < 4; nt++) {
                float p0 = fast_exp2(s[nt][m][0]);
                float p1 = fast_exp2(s[nt][m][1]);
                float p2 = fast_exp2(s[nt][m][2]);
                float p3 = fast_exp2(s[nt][m][3]);
                l_part[m] += (p0 + p1) + (p2 + p3);
                uint2 w;
                w.x = pk_bf16(p0, p1);
                w.y = pk_bf16(p2, p3);
                // P[q = m*16+l15][key = nt*16 + quad*4 .. +3]
                *(uint2*)&sPw[(m * 16 + l15) * PST + nt * 16 + quad * 4] = w;
            }

        // --- PV from sV[cur] (UNCHANGED layout: P read as [q][key]) ---
#pragma unroll
        for (int c = 0; c < 2; c++) {
            bf16x8 pf0 = *(const bf16x8*)&sPw[(0 * 16 + l15) * PST + c * 32 + quad * 8];
            bf16x8 pf1 = *(const bf16x8*)&sPw[(1 * 16 + l15) * PST + c * 32 + quad * 8];
#pragma unroll
            for (int nt = 0; nt < 4; nt++) {
                bf16x8 vf = *(const bf16x8*)&sV[cur][(nt * 16 + l15) * 72 + c * 32 + quad * 8];
                oacc[0][nt] = __builtin_amdgcn_mfma_f32_16x16x32_bf16(pf0, vf, oacc[0][nt], 0, 0, 0);
                oacc[1][nt] = __builtin_amdgcn_mfma_f32_16x16x32_bf16(pf1, vf, oacc[1][nt], 0, 0, 0);
            }
        }

        // --- stage next tile into the other buffer; single barrier ---
        if (has_next) {
            const int nxt = cur ^ 1;
            *(uint4*)&sK[nxt][srow * 72 + scol]     = nkv0;
            *(uint4*)&sK[nxt][srow * 72 + scol + 8] = nkv1;
            *(uint4*)&sV[nxt][srow * 72 + scol]     = nvv0;
            *(uint4*)&sV[nxt][srow * 72 + scol + 8] = nvv1;
        }
        __syncthreads();
        cur ^= 1;
    }

    // l reduction: full sum over 64 keys/quad-groups, replicated per l15.
    float lf[2];
#pragma unroll
    for (int m = 0; m < 2; m++) {
        float l = l_part[m];
        l += __shfl_xor(l, 16);
        l += __shfl_xor(l, 32);
        lf[m] = l;                       // value at lane L = l for q=m*16+(L&15)
    }
#pragma unroll
    for (int m = 0; m < 2; m++) {
        float l_i[4];
#pragma unroll
        for (int r = 0; r < 4; r++)      // need q = m*16 + quad*4 + r
            l_i[r] = __shfl(lf[m], (lane & 48) | (quad * 4 + r));
#pragma unroll
        for (int nt = 0; nt < 4; nt++) {
            int col = head * DK + nt * 16 + l15;
#pragma unroll
            for (int r = 0; r < 4; r++) {
                int row = q0 + wave * 32 + m * 16 + quad * 4 + r;
                float o = oacc[m][nt][r] / l_i[r];
                u16 h = f2h(o);
                AOh[(size_t)row * DMODEL + col] = h;
                AOl[(size_t)row * DMODEL + col] = f2h(o - h2f(h));
            }
        }
    }
}

// ---------------------------------------------------------------------------
extern "C" void kernel_launch(void* const* d_in, const int* in_sizes, int n_in,
                              void* d_out, int out_size, void* d_ws, size_t ws_size,
                              hipStream_t stream) {
    const float* query = (const float*)d_in[0];
    const float* key_t = (const float*)d_in[1];
    const float* value = (const float*)d_in[2];
    const float* wq    = (const float*)d_in[3];
    const float* wk    = (const float*)d_in[4];
    const float* wv    = (const float*)d_in[5];
    const float* wo    = (const float*)d_in[6];
    float* out = (float*)d_out;

    const size_t ACT_N = (size_t)SEQ * DMODEL;
    const size_t W_N   = (size_t)DMODEL * DMODEL;
    const size_t NEED  = 4 * ACT_N * sizeof(float);   // 64 MB (verified available)

    if (d_ws == nullptr || ws_size < NEED) {
        fallback_marker<<<dim3((out_size + 255) / 256), dim3(256), 0, stream>>>(out, out_size);
        return;
    }

    u16* ACT_HI = (u16*)d_ws;          // 8 MB  (phased, fp16 hi)
    u16* ACT_LO = ACT_HI + ACT_N;      // 8 MB  (fp16 lo)
    u16* W_HI   = ACT_LO + ACT_N;      // 2 MB  (phased, fp16 hi)
    u16* W_LO   = W_HI + W_N;          // 2 MB  (fp16 lo)
    u16* Qb     = W_LO + W_N;          // 8 MB  bf16 Q (pre-scaled 1/8*log2e)
    u16* Kb     = Qb + ACT_N;          // 8 MB  bf16 K
    u16* Vt     = Kb + ACT_N;          // 8 MB  bf16 V^T [DMODEL][SEQ]
    u16* AO_HI  = Vt + ACT_N;          // 8 MB  fp16 AO hi
    u16* AO_LO  = AO_HI + ACT_N;       // 8 MB  fp16 AO lo

    const int ACT4 = (int)(ACT_N / 4);
    const int W4   = (int)(W_N / 4);
    dim3 blk(256);
    dim3 pairg((ACT4 + 255) / 256, 2);
    dim3 wg((W4 + 255) / 256);

    const float QSCALE = 0.125f * 1.44269504f;   // 1/sqrt(dk) * log2(e)

    // Q = query @ wq^T : A = query hi/lo, B = wq hi
    split_pair<<<pairg, blk, 0, stream>>>(query, ACT_HI, ACT_LO, ACT4, wq, W_HI, W_LO, W4);
    proj_hl_bf<<<dim3(SEQ / 128, DMODEL / 64), blk, 0, stream>>>(
        ACT_HI, ACT_LO, W_HI, Qb, DMODEL, QSCALE);

    // K = key @ wk^T : A = key hi/lo, B = wk hi
    split_pair<<<pairg, blk, 0, stream>>>(key_t, ACT_HI, ACT_LO, ACT4, wk, W_HI, W_LO, W4);
    proj_hl_bf<<<dim3(SEQ / 128, DMODEL / 64), blk, 0, stream>>>(
        ACT_HI, ACT_LO, W_HI, Kb, DMODEL, 1.0f);

    // V^T = wv @ value^T : A = wv hi/lo, B = value hi
    split_pair<<<pairg, blk, 0, stream>>>(value, ACT_HI, ACT_LO, ACT4, wv, W_HI, W_LO, W4);
    proj_hl_bf<<<dim3(DMODEL / 128, SEQ / 64), blk, 0, stream>>>(
        W_HI, W_LO, ACT_HI, Vt, SEQ, 1.0f);

    attn_mfma<<<dim3(SEQ / 128, NHEAD), blk, 0, stream>>>(Qb, Kb, Vt, AO_HI, AO_LO);

    // out = AO @ wo^T : A = AO hi/lo (fp16), B = wo hi
    split_kernel<<<wg, blk, 0, stream>>>(wo, W_HI, W_LO, W4);
    proj_hl_f32<<<dim3(SEQ / 128, DMODEL / 64), blk, 0, stream>>>(
        AO_HI, AO_LO, W_HI, out);
}

// Round 9
// 291.683 us; speedup vs baseline: 1.4070x; 1.1482x over previous
//
#include <hip/hip_runtime.h>
#include <hip/hip_bf16.h>
#include <hip/hip_fp16.h>
#include <cstdint>
#include <math.h>

#define DMODEL 1024
#define SEQ    4096
#define NHEAD  16
#define DK     64

typedef __attribute__((ext_vector_type(8))) short bf16x8;       // 8 bf16 = 4 VGPRs
typedef __attribute__((ext_vector_type(8))) _Float16 f16x8;     // 8 fp16 = 4 VGPRs
typedef __attribute__((ext_vector_type(4))) float f32x4;
typedef unsigned short u16;

__device__ __forceinline__ u16 f2bf(float f) {
    union { float f; unsigned int u; } v; v.f = f;
    unsigned int u = v.u;
    u += 0x7FFFu + ((u >> 16) & 1u);   // round-to-nearest-even
    return (u16)(u >> 16);
}
__device__ __forceinline__ float bf2f(u16 h) {
    union { unsigned int u; float f; } v; v.u = ((unsigned int)h) << 16;
    return v.f;
}
__device__ __forceinline__ u16 f2h(float f) {
    __half h = __float2half_rn(f);
    union { __half h; u16 u; } v; v.h = h; return v.u;
}
__device__ __forceinline__ float h2f(u16 x) {
    union { u16 u; __half h; } v; v.u = x;
    return __half2float(v.h);
}
__device__ __forceinline__ unsigned int pk_bf16(float a, float b) {
    union { __hip_bfloat162 h; unsigned int u; } v;
    v.h = __float22bfloat162_rn(make_float2(a, b));
    return v.u;
}
// raw v_exp_f32 = 2^x (Q is pre-scaled by 1/8 * log2(e) so this computes e^s)
__device__ __forceinline__ float fast_exp2(float x) {
    float r; asm("v_exp_f32 %0, %1" : "=v"(r) : "v"(x)); return r;
}

// Fallback marker if ws_size too small (diagnostic).
__global__ __launch_bounds__(256) void fallback_marker(float* __restrict__ out, int n) {
    int i = blockIdx.x * 256 + threadIdx.x;
    if (i < n) out[i] = (i == 0) ? 12345.0f : 0.0f;
}

// ---------------------------------------------------------------------------
// Fused fp32 -> fp16(hi only) conversion for all 6 QKV-phase tensors.
// Precision ledger: Q/K/V-proj outputs are bf16-rounded (rel ~1.1e-3), so
// the dropped lo terms (~2.8e-4) are under that floor.
// ---------------------------------------------------------------------------
__global__ __launch_bounds__(256) void split_all(const float* __restrict__ q,
                                                 const float* __restrict__ k,
                                                 const float* __restrict__ v,
                                                 const float* __restrict__ wq,
                                                 const float* __restrict__ wk,
                                                 const float* __restrict__ wv,
                                                 u16* __restrict__ qh,
                                                 u16* __restrict__ kh,
                                                 u16* __restrict__ vh,
                                                 u16* __restrict__ wqh,
                                                 u16* __restrict__ wkh,
                                                 u16* __restrict__ wvh,
                                                 int act_n4, int w_n4) {
    int i = blockIdx.x * 256 + threadIdx.x;
    const float* src; u16* dst; int n4;
    switch (blockIdx.y) {
        case 0:  src = q;  dst = qh;  n4 = act_n4; break;
        case 1:  src = k;  dst = kh;  n4 = act_n4; break;
        case 2:  src = v;  dst = vh;  n4 = act_n4; break;
        case 3:  src = wq; dst = wqh; n4 = w_n4;   break;
        case 4:  src = wk; dst = wkh; n4 = w_n4;   break;
        default: src = wv; dst = wvh; n4 = w_n4;   break;
    }
    if (i < n4) {
        float4 f = ((const float4*)src)[i];
        ushort4 h; h.x = f2h(f.x); h.y = f2h(f.y); h.z = f2h(f.z); h.w = f2h(f.w);
        ((ushort4*)dst)[i] = h;
    }
}

// fp32 -> fp16 hi/lo split (only wo's B-side... no: wo needs hi only; AO's
// hi/lo comes from attn directly). split_hi handles wo.
__global__ __launch_bounds__(256) void split_hi(const float* __restrict__ in,
                                                u16* __restrict__ hi, int n4) {
    int i = blockIdx.x * 256 + threadIdx.x;
    if (i < n4) {
        float4 f = ((const float4*)in)[i];
        ushort4 h; h.x = f2h(f.x); h.y = f2h(f.y); h.z = f2h(f.z); h.w = f2h(f.w);
        ((ushort4*)hi)[i] = h;
    }
}

// ---------------------------------------------------------------------------
// 1-term fp16 MFMA GEMM core: C = Ah * Bh. Strict subset of the proven r8
// 2-term core (al reads + 2nd MFMA removed). 128x64 tile, 256 threads,
// 2-barrier loop, 16 MFMA/kstep, LDS 27.6 KB (5 blocks/CU).
// ---------------------------------------------------------------------------
__device__ __forceinline__ void gemm_core_f16_1t(const u16* __restrict__ aHi,
                                                 const u16* __restrict__ bHi,
                                                 int bm, int bn,
                                                 f32x4 (&acc)[2][4]) {
    __shared__ u16 sAh[128 * 72];   // 18 KB
    __shared__ u16 sBh[64 * 72];    // 9 KB   (27.6 KB total)

    const int tid  = threadIdx.x;
    const int wave = tid >> 6;
    const int lane = tid & 63;
    const int quad = lane >> 4;
    const int l15  = lane & 15;
    const int srow = tid >> 2;          // 0..63
    const int scol = (tid & 3) * 16;    // 0,16,32,48

    const u16* pA0 = aHi + (size_t)(bm + srow) * DMODEL + scol;
    const u16* pA1 = aHi + (size_t)(bm + 64 + srow) * DMODEL + scol;
    const u16* pB  = bHi + (size_t)(bn + srow) * DMODEL + scol;

    for (int k0 = 0; k0 < DMODEL; k0 += 64) {
        uint4 a00 = *(const uint4*)(pA0 + k0);
        uint4 a01 = *(const uint4*)(pA0 + k0 + 8);
        uint4 a10 = *(const uint4*)(pA1 + k0);
        uint4 a11 = *(const uint4*)(pA1 + k0 + 8);
        uint4 b0  = *(const uint4*)(pB + k0);
        uint4 b1  = *(const uint4*)(pB + k0 + 8);

        __syncthreads();
        *(uint4*)&sAh[srow * 72 + scol]            = a00;
        *(uint4*)&sAh[srow * 72 + scol + 8]        = a01;
        *(uint4*)&sAh[(64 + srow) * 72 + scol]     = a10;
        *(uint4*)&sAh[(64 + srow) * 72 + scol + 8] = a11;
        *(uint4*)&sBh[srow * 72 + scol]            = b0;
        *(uint4*)&sBh[srow * 72 + scol + 8]        = b1;
        __syncthreads();

#pragma unroll
        for (int c = 0; c < 2; c++) {
            f16x8 ah[2];
#pragma unroll
            for (int m = 0; m < 2; m++) {
                const int aoff = (wave * 32 + m * 16 + l15) * 72 + c * 32 + quad * 8;
                ah[m] = *(const f16x8*)&sAh[aoff];
            }
#pragma unroll
            for (int nt = 0; nt < 4; nt++) {
                const int boff = (nt * 16 + l15) * 72 + c * 32 + quad * 8;
                f16x8 bhf = *(const f16x8*)&sBh[boff];
#pragma unroll
                for (int m = 0; m < 2; m++)
                    acc[m][nt] = __builtin_amdgcn_mfma_f32_16x16x32_f16(ah[m], bhf, acc[m][nt], 0, 0, 0);
            }
        }
    }
}

// ---------------------------------------------------------------------------
// Fused Q/K/V projection: grid (512, 3) = 1536 blocks (6/CU grid-side, LDS
// caps at 5 -> ~20 waves/CU). z=0: Q = query@wq^T (scaled); z=1: K; z=2:
// V^T = wv@value^T. XCD-bijective swizzle over all 1536 (192-block chunks).
// ---------------------------------------------------------------------------
__global__ __launch_bounds__(256) void proj_qkv(const u16* __restrict__ qh,
                                                const u16* __restrict__ kh,
                                                const u16* __restrict__ vh,
                                                const u16* __restrict__ wqh,
                                                const u16* __restrict__ wkh,
                                                const u16* __restrict__ wvh,
                                                u16* __restrict__ Qb,
                                                u16* __restrict__ Kb,
                                                u16* __restrict__ Vt,
                                                float qscale) {
    const int lin = blockIdx.y * gridDim.x + blockIdx.x;   // 0..1535
    const int swz = (lin & 7) * 192 + (lin >> 3);          // bijective
    const int z   = swz >> 9;                              // 0..2
    const int bx  = swz & 511;

    const u16 *A, *B; u16* C; int bm, bn, ldc; float scale;
    if (z == 0)      { A = qh;  B = wqh; C = Qb; bm = (bx & 31) * 128; bn = (bx >> 5) * 64; ldc = DMODEL; scale = qscale; }
    else if (z == 1) { A = kh;  B = wkh; C = Kb; bm = (bx & 31) * 128; bn = (bx >> 5) * 64; ldc = DMODEL; scale = 1.0f; }
    else             { A = wvh; B = vh;  C = Vt; bm = (bx & 7) * 128;  bn = (bx >> 3) * 64; ldc = SEQ;    scale = 1.0f; }

    f32x4 acc[2][4] = {};
    gemm_core_f16_1t(A, B, bm, bn, acc);

    const int lane = threadIdx.x & 63;
    const int wave = threadIdx.x >> 6;
    const int quad = lane >> 4;
    const int l15  = lane & 15;
#pragma unroll
    for (int m = 0; m < 2; m++)
#pragma unroll
        for (int nt = 0; nt < 4; nt++) {
            int col = bn + nt * 16 + l15;
#pragma unroll
            for (int r = 0; r < 4; r++) {
                int row = bm + wave * 32 + m * 16 + quad * 4 + r;
                C[(size_t)row * ldc + col] = f2bf(acc[m][nt][r] * scale);
            }
        }
}

// ---------------------------------------------------------------------------
// FP16 2-term MFMA GEMM core (r8 PROVEN): C = (Ah+Al)*Bh. Used for the
// output projection only (A = AO hi/lo fp16 from attn, B = wo hi).
// ---------------------------------------------------------------------------
__device__ __forceinline__ void gemm_core_fp16(const u16* __restrict__ aHi,
                                               const u16* __restrict__ aLo,
                                               const u16* __restrict__ bHi,
                                               int bm, int bn,
                                               f32x4 (&acc)[2][4]) {
    __shared__ u16 sAh[128 * 72], sAl[128 * 72];   // 18 KB each
    __shared__ u16 sBh[64 * 72];                   // 9 KB      (45 KB total)

    const int tid  = threadIdx.x;
    const int wave = tid >> 6;
    const int lane = tid & 63;
    const int quad = lane >> 4;
    const int l15  = lane & 15;
    const int srow = tid >> 2;          // 0..63
    const int scol = (tid & 3) * 16;    // 0,16,32,48

    const u16* pAh0 = aHi + (size_t)(bm + srow) * DMODEL + scol;
    const u16* pAh1 = aHi + (size_t)(bm + 64 + srow) * DMODEL + scol;
    const u16* pAl0 = aLo + (size_t)(bm + srow) * DMODEL + scol;
    const u16* pAl1 = aLo + (size_t)(bm + 64 + srow) * DMODEL + scol;
    const u16* pBh  = bHi + (size_t)(bn + srow) * DMODEL + scol;

    for (int k0 = 0; k0 < DMODEL; k0 += 64) {
        uint4 ah00 = *(const uint4*)(pAh0 + k0);
        uint4 ah01 = *(const uint4*)(pAh0 + k0 + 8);
        uint4 ah10 = *(const uint4*)(pAh1 + k0);
        uint4 ah11 = *(const uint4*)(pAh1 + k0 + 8);
        uint4 al00 = *(const uint4*)(pAl0 + k0);
        uint4 al01 = *(const uint4*)(pAl0 + k0 + 8);
        uint4 al10 = *(const uint4*)(pAl1 + k0);
        uint4 al11 = *(const uint4*)(pAl1 + k0 + 8);
        uint4 bh0  = *(const uint4*)(pBh + k0);
        uint4 bh1  = *(const uint4*)(pBh + k0 + 8);

        __syncthreads();
        *(uint4*)&sAh[srow * 72 + scol]            = ah00;
        *(uint4*)&sAh[srow * 72 + scol + 8]        = ah01;
        *(uint4*)&sAh[(64 + srow) * 72 + scol]     = ah10;
        *(uint4*)&sAh[(64 + srow) * 72 + scol + 8] = ah11;
        *(uint4*)&sAl[srow * 72 + scol]            = al00;
        *(uint4*)&sAl[srow * 72 + scol + 8]        = al01;
        *(uint4*)&sAl[(64 + srow) * 72 + scol]     = al10;
        *(uint4*)&sAl[(64 + srow) * 72 + scol + 8] = al11;
        *(uint4*)&sBh[srow * 72 + scol]            = bh0;
        *(uint4*)&sBh[srow * 72 + scol + 8]        = bh1;
        __syncthreads();

#pragma unroll
        for (int c = 0; c < 2; c++) {
            f16x8 ah[2], al[2];
#pragma unroll
            for (int m = 0; m < 2; m++) {
                const int aoff = (wave * 32 + m * 16 + l15) * 72 + c * 32 + quad * 8;
                ah[m] = *(const f16x8*)&sAh[aoff];
                al[m] = *(const f16x8*)&sAl[aoff];
            }
#pragma unroll
            for (int nt = 0; nt < 4; nt++) {
                const int boff = (nt * 16 + l15) * 72 + c * 32 + quad * 8;
                f16x8 bhf = *(const f16x8*)&sBh[boff];
#pragma unroll
                for (int m = 0; m < 2; m++) {
                    acc[m][nt] = __builtin_amdgcn_mfma_f32_16x16x32_f16(ah[m], bhf, acc[m][nt], 0, 0, 0);
                    acc[m][nt] = __builtin_amdgcn_mfma_f32_16x16x32_f16(al[m], bhf, acc[m][nt], 0, 0, 0);
                }
            }
        }
    }
}

__global__ __launch_bounds__(256) void proj_hl_f32(const u16* __restrict__ aHi,
                                                   const u16* __restrict__ aLo,
                                                   const u16* __restrict__ bHi,
                                                   float* __restrict__ C) {
    const int bm = blockIdx.x * 128;
    const int bn = blockIdx.y * 64;
    f32x4 acc[2][4] = {};
    gemm_core_fp16(aHi, aLo, bHi, bm, bn, acc);
    const int lane = threadIdx.x & 63;
    const int wave = threadIdx.x >> 6;
    const int quad = lane >> 4;
    const int l15  = lane & 15;
#pragma unroll
    for (int m = 0; m < 2; m++)
#pragma unroll
        for (int nt = 0; nt < 4; nt++) {
            int col = bn + nt * 16 + l15;
#pragma unroll
            for (int r = 0; r < 4; r++) {
                int row = bm + wave * 32 + m * 16 + quad * 4 + r;
                C[(size_t)row * DMODEL + col] = acc[m][nt][r];
            }
        }
}

// ---------------------------------------------------------------------------
// MFMA flash attention v7 (r7/r8 PROVEN, byte-identical): swapped QK^T,
// 256 thr, wave owns 32 q-rows, dbuf K/V, single barrier, XCD swizzle.
// AO written as fp16 hi/lo.
// ---------------------------------------------------------------------------
#define PST 72   // sP row stride (u16); rows 16B-aligned for b128 reads

__global__ __launch_bounds__(256) void attn_mfma(const u16* __restrict__ Q,
                                                 const u16* __restrict__ K,
                                                 const u16* __restrict__ Vt,
                                                 u16* __restrict__ AOh,
                                                 u16* __restrict__ AOl) {
    __shared__ u16 sK[2][64 * 72];       // K tile [key][d]   9 KB x2
    __shared__ u16 sV[2][64 * 72];       // V tile [d][key]   9 KB x2
    __shared__ u16 sP[4 * 32 * PST];     // per-wave P [32 q][64 key] 18 KB

    // XCD-aware bijective swizzle: grid (32,16) = 512 blocks, chunk = 64.
    const int lin  = blockIdx.y * gridDim.x + blockIdx.x;
    const int swz  = (lin & 7) * 64 + (lin >> 3);
    const int head = swz >> 5;           // 0..15; 2 whole heads per XCD
    const int q0   = (swz & 31) * 128;

    const int tid  = threadIdx.x;
    const int wave = tid >> 6;
    const int lane = tid & 63;
    const int quad = lane >> 4;
    const int l15  = lane & 15;
    const int srow = tid >> 2;           // 0..63
    const int scol = (tid & 3) * 16;     // 0,16,32,48

    bf16x8 qf[2][2];
#pragma unroll
    for (int m = 0; m < 2; m++) {
        const u16* qb = Q + (size_t)(q0 + wave * 32 + m * 16 + l15) * DMODEL + head * DK;
        qf[m][0] = *(const bf16x8*)(qb + quad * 8);
        qf[m][1] = *(const bf16x8*)(qb + 32 + quad * 8);
    }

    f32x4 oacc[2][4] = {};
    float l_part[2] = {0.0f, 0.0f};      // per-lane: q = m*16 + l15, 16 keys

    const u16* Kst = K  + (size_t)srow * DMODEL + head * DK + scol;
    const u16* Vst = Vt + (size_t)(head * DK + srow) * SEQ + scol;
    u16* sPw = sP + wave * 32 * PST;

    // Prologue: stage tile 0 into buffer 0.
    {
        uint4 kv0 = *(const uint4*)(Kst);
        uint4 kv1 = *(const uint4*)(Kst + 8);
        uint4 vv0 = *(const uint4*)(Vst);
        uint4 vv1 = *(const uint4*)(Vst + 8);
        *(uint4*)&sK[0][srow * 72 + scol]     = kv0;
        *(uint4*)&sK[0][srow * 72 + scol + 8] = kv1;
        *(uint4*)&sV[0][srow * 72 + scol]     = vv0;
        *(uint4*)&sV[0][srow * 72 + scol + 8] = vv1;
    }
    __syncthreads();

    int cur = 0;
    for (int k0 = 0; k0 < SEQ; k0 += 64) {
        // Issue next tile's global loads first (hide L2 latency under compute).
        uint4 nkv0, nkv1, nvv0, nvv1;
        const bool has_next = (k0 + 64 < SEQ);
        if (has_next) {
            nkv0 = *(const uint4*)(Kst + (size_t)(k0 + 64) * DMODEL);
            nkv1 = *(const uint4*)(Kst + (size_t)(k0 + 64) * DMODEL + 8);
            nvv0 = *(const uint4*)(Vst + k0 + 64);
            nvv1 = *(const uint4*)(Vst + k0 + 64 + 8);
        }

        // --- QK^T SWAPPED: s[nt][m] = K_frag * Q_frag  (fragments unchanged)
        // D[row=key(nt*16+quad*4+r)][col=q(m*16+l15)]
        f32x4 s[4][2] = {};
#pragma unroll
        for (int nt = 0; nt < 4; nt++) {
            bf16x8 kf0 = *(const bf16x8*)&sK[cur][(nt * 16 + l15) * 72 + quad * 8];
            bf16x8 kf1 = *(const bf16x8*)&sK[cur][(nt * 16 + l15) * 72 + 32 + quad * 8];
#pragma unroll
            for (int m = 0; m < 2; m++) {
                s[nt][m] = __builtin_amdgcn_mfma_f32_16x16x32_bf16(kf0, qf[m][0], s[nt][m], 0, 0, 0);
                s[nt][m] = __builtin_amdgcn_mfma_f32_16x16x32_bf16(kf1, qf[m][1], s[nt][m], 0, 0, 0);
            }
        }

        // --- softmax numerator: exp, accumulate l, ONE b64 store per (m,nt)
#pragma unroll
        for (int m = 0; m < 2; m++)
#pragma unroll
            for (int nt = 0; nt < 4; nt++) {
                float p0 = fast_exp2(s[nt][m][0]);
                float p1 = fast_exp2(s[nt][m][1]);
                float p2 = fast_exp2(s[nt][m][2]);
                float p3 = fast_exp2(s[nt][m][3]);
                l_part[m] += (p0 + p1) + (p2 + p3);
                uint2 w;
                w.x = pk_bf16(p0, p1);
                w.y = pk_bf16(p2, p3);
                // P[q = m*16+l15][key = nt*16 + quad*4 .. +3]
                *(uint2*)&sPw[(m * 16 + l15) * PST + nt * 16 + quad * 4] = w;
            }

        // --- PV from sV[cur] (UNCHANGED layout: P read as [q][key]) ---
#pragma unroll
        for (int c = 0; c < 2; c++) {
            bf16x8 pf0 = *(const bf16x8*)&sPw[(0 * 16 + l15) * PST + c * 32 + quad * 8];
            bf16x8 pf1 = *(const bf16x8*)&sPw[(1 * 16 + l15) * PST + c * 32 + quad * 8];
#pragma unroll
            for (int nt = 0; nt < 4; nt++) {
                bf16x8 vf = *(const bf16x8*)&sV[cur][(nt * 16 + l15) * 72 + c * 32 + quad * 8];
                oacc[0][nt] = __builtin_amdgcn_mfma_f32_16x16x32_bf16(pf0, vf, oacc[0][nt], 0, 0, 0);
                oacc[1][nt] = __builtin_amdgcn_mfma_f32_16x16x32_bf16(pf1, vf, oacc[1][nt], 0, 0, 0);
            }
        }

        // --- stage next tile into the other buffer; single barrier ---
        if (has_next) {
            const int nxt = cur ^ 1;
            *(uint4*)&sK[nxt][srow * 72 + scol]     = nkv0;
            *(uint4*)&sK[nxt][srow * 72 + scol + 8] = nkv1;
            *(uint4*)&sV[nxt][srow * 72 + scol]     = nvv0;
            *(uint4*)&sV[nxt][srow * 72 + scol + 8] = nvv1;
        }
        __syncthreads();
        cur ^= 1;
    }

    // l reduction: full sum over 64 keys/quad-groups, replicated per l15.
    float lf[2];
#pragma unroll
    for (int m = 0; m < 2; m++) {
        float l = l_part[m];
        l += __shfl_xor(l, 16);
        l += __shfl_xor(l, 32);
        lf[m] = l;                       // value at lane L = l for q=m*16+(L&15)
    }
#pragma unroll
    for (int m = 0; m < 2; m++) {
        float l_i[4];
#pragma unroll
        for (int r = 0; r < 4; r++)      // need q = m*16 + quad*4 + r
            l_i[r] = __shfl(lf[m], (lane & 48) | (quad * 4 + r));
#pragma unroll
        for (int nt = 0; nt < 4; nt++) {
            int col = head * DK + nt * 16 + l15;
#pragma unroll
            for (int r = 0; r < 4; r++) {
                int row = q0 + wave * 32 + m * 16 + quad * 4 + r;
                float o = oacc[m][nt][r] / l_i[r];
                u16 h = f2h(o);
                AOh[(size_t)row * DMODEL + col] = h;
                AOl[(size_t)row * DMODEL + col] = f2h(o - h2f(h));
            }
        }
    }
}

// ---------------------------------------------------------------------------
extern "C" void kernel_launch(void* const* d_in, const int* in_sizes, int n_in,
                              void* d_out, int out_size, void* d_ws, size_t ws_size,
                              hipStream_t stream) {
    const float* query = (const float*)d_in[0];
    const float* key_t = (const float*)d_in[1];
    const float* value = (const float*)d_in[2];
    const float* wq    = (const float*)d_in[3];
    const float* wk    = (const float*)d_in[4];
    const float* wv    = (const float*)d_in[5];
    const float* wo    = (const float*)d_in[6];
    float* out = (float*)d_out;

    const size_t ACT_N = (size_t)SEQ * DMODEL;       // 4M elems
    const size_t W_N   = (size_t)DMODEL * DMODEL;    // 1M elems
    const size_t NEED  = 4 * ACT_N * sizeof(float);  // 64 MB (verified available)

    if (d_ws == nullptr || ws_size < NEED) {
        fallback_marker<<<dim3((out_size + 255) / 256), dim3(256), 0, stream>>>(out, out_size);
        return;
    }

    // Buffer map (54 MB used of 64):
    u16* ACT0 = (u16*)d_ws;            // 0-8 MB   query_hi -> AO_hi
    u16* ACT1 = ACT0 + ACT_N;          // 8-16 MB  key_hi   -> AO_lo
    u16* ACT2 = ACT1 + ACT_N;          // 16-24 MB value_hi
    u16* W0   = ACT2 + ACT_N;          // 24-26 MB wq_hi -> wo_hi
    u16* W1   = W0 + W_N;              // 26-28 MB wk_hi
    u16* W2   = W1 + W_N;              // 28-30 MB wv_hi
    u16* Qb   = W2 + W_N;              // 30-38 MB bf16 Q (pre-scaled)
    u16* Kb   = Qb + ACT_N;            // 38-46 MB bf16 K
    u16* Vt   = Kb + ACT_N;            // 46-54 MB bf16 V^T [DMODEL][SEQ]

    const int ACT4 = (int)(ACT_N / 4);
    const int W4   = (int)(W_N / 4);
    dim3 blk(256);

    const float QSCALE = 0.125f * 1.44269504f;   // 1/sqrt(dk) * log2(e)

    // 1) one fused hi-only fp16 conversion of all six QKV-phase tensors
    split_all<<<dim3((ACT4 + 255) / 256, 6), blk, 0, stream>>>(
        query, key_t, value, wq, wk, wv,
        ACT0, ACT1, ACT2, W0, W1, W2, ACT4, W4);

    // 2) fused Q/K/V projections (1536 blocks, 1-term fp16)
    proj_qkv<<<dim3(512, 3), blk, 0, stream>>>(
        ACT0, ACT1, ACT2, W0, W1, W2, Qb, Kb, Vt, QSCALE);

    // 3) attention (reads Qb/Kb/Vt; overwrites dead query/key regions with AO)
    attn_mfma<<<dim3(SEQ / 128, NHEAD), blk, 0, stream>>>(Qb, Kb, Vt, ACT0, ACT1);

    // 4) wo hi-only (into dead wq slot)
    split_hi<<<dim3((W4 + 255) / 256), blk, 0, stream>>>(wo, W0, W4);

    // 5) output projection: A = AO hi/lo (fp16 2-term), B = wo hi
    proj_hl_f32<<<dim3(SEQ / 128, DMODEL / 64), blk, 0, stream>>>(
        ACT0, ACT1, W0, out);
}